// Round 4
// baseline (1064.090 us; speedup 1.0000x reference)
//
#include <hip/hip_runtime.h>

#define N_NODES_C 50000
#define N_EDGES_C 1600000
#define EPS_C 1e-5f

typedef __attribute__((ext_vector_type(8))) short bf16x8;
typedef __attribute__((ext_vector_type(4))) float f32x4;

static __device__ __forceinline__ unsigned short rne_bf(float f) {
    union { float f; unsigned int u; } v; v.f = f;
    unsigned int r = v.u + 0x7fffu + ((v.u >> 16) & 1u);  // RNE
    return (unsigned short)(r >> 16);
}
static __device__ __forceinline__ float bf2f(unsigned short h) {
    union { unsigned int u; float f; } v; v.u = ((unsigned int)h) << 16;
    return v.f;
}
static __device__ __forceinline__ void splitf(float x, short& hi, short& lo) {
    unsigned short h = rne_bf(x);
    hi = (short)h;
    lo = (short)rne_bf(x - bf2f(h));
}
static __device__ __forceinline__ void ld8split(const float* p, float scale,
                                                bf16x8& hi, bf16x8& lo) {
    float4 a = *reinterpret_cast<const float4*>(p);
    float4 b = *reinterpret_cast<const float4*>(p + 4);
    float v[8] = {a.x, a.y, a.z, a.w, b.x, b.y, b.z, b.w};
#pragma unroll
    for (int i = 0; i < 8; ++i) {
        short h, l;
        splitf(v[i] * scale, h, l);
        hi[i] = h; lo[i] = l;
    }
}

// 3-term split product: acc += (Ah+Al)@(Bh+Bl) minus lo@lo
#define MFMA3(acc, wh, wl, bh, bl)                                            \
    acc = __builtin_amdgcn_mfma_f32_16x16x32_bf16(wh, bh, acc, 0, 0, 0);      \
    acc = __builtin_amdgcn_mfma_f32_16x16x32_bf16(wl, bh, acc, 0, 0, 0);      \
    acc = __builtin_amdgcn_mfma_f32_16x16x32_bf16(wh, bl, acc, 0, 0, 0);

// ===========================================================================
// Pre-split x (50000x32 f32) into bf16 hi/lo planes (removes ~64x redundant
// per-edge conversion in the edge kernel).
// ===========================================================================
__global__ __launch_bounds__(256) void prep_x_kernel(
    const float* __restrict__ x,
    unsigned short* __restrict__ xh, unsigned short* __restrict__ xl)
{
    const int i = blockIdx.x * 256 + threadIdx.x;  // float4 index
    if (i >= (N_NODES_C * 32) / 4) return;
    float4 v = reinterpret_cast<const float4*>(x)[i];
    short4 h, l;
    splitf(v.x, h.x, l.x); splitf(v.y, h.y, l.y);
    splitf(v.z, h.z, l.z); splitf(v.w, h.w, l.w);
    reinterpret_cast<short4*>(xh)[i] = h;
    reinterpret_cast<short4*>(xl)[i] = l;
}

// ===========================================================================
// Edge MLP, hidden-split across 4 waves (wave w owns cols [32w,32w+32)).
// Layer-1 as h^T = W1^T @ in^T (frag layouts HW-validated in R3).
// x segments read pre-split planes; ea split in-kernel; u hoisted.
// ===========================================================================
__global__ __launch_bounds__(256, 4) void edge_kernel(
    const unsigned short* __restrict__ xh, const unsigned short* __restrict__ xl,
    const float* __restrict__ ea, const float* __restrict__ u,
    const int* __restrict__ src, const int* __restrict__ dst,
    const float* __restrict__ W1, const float* __restrict__ b1,
    const float* __restrict__ W2, const float* __restrict__ b2,
    const float* __restrict__ gamma, const float* __restrict__ beta,
    float* __restrict__ e_out, float* __restrict__ agg, float* __restrict__ cnt,
    float* __restrict__ esum)
{
    // per-wave hidden slab: [wave][edge-row 32][hi/lo][k-local 32 pad 40]
    __shared__ __attribute__((aligned(16))) unsigned short hs[4][32][2][40];
    // cross-wave layer-2 partials, double-buffered (pad 17)
    __shared__ float red[2][4][32][17];
    __shared__ float esr[4][16];

    const int tid = threadIdx.x;
    const int w = tid >> 6, l = tid & 63, g = l >> 4, c = l & 15;
    const int csw = c >> 2;
    const bool glt2 = (g < 2);
    const int off8 = 8 * (g & 1);

    // ---- W1 fragments (this wave's 2 hidden n-tiles), hi/lo, in registers
    bf16x8 w1h[3][2], w1l[3][2];
#pragma unroll
    for (int kk = 0; kk < 3; ++kk)
#pragma unroll
        for (int nt = 0; nt < 2; ++nt) {
            bf16x8 h, lo;
#pragma unroll
            for (int j = 0; j < 8; ++j) {
                float f = W1[(size_t)(32 * kk + 8 * g + j) * 128 + 32 * w + 16 * nt + c];
                short sh, sl; splitf(f, sh, sl);
                h[j] = sh; lo[j] = sl;
            }
            w1h[kk][nt] = h; w1l[kk][nt] = lo;
        }

    // ---- W2 slice fragments (K rows [32w,32w+32)), hi/lo
    bf16x8 w2h, w2l;
    {
        bf16x8 h, lo;
#pragma unroll
        for (int j = 0; j < 8; ++j) {
            float f = W2[(size_t)(32 * w + 8 * g + j) * 16 + c];
            short sh, sl; splitf(f, sh, sl);
            h[j] = sh; lo[j] = sl;
        }
        w2h = h; w2l = lo;
    }

    // ---- hoisted u fragments (used by lanes g>=2 in kk2)
    bf16x8 uh, ul;
    ld8split(u + off8, 1.f, uh, ul);

    // ---- b1 values this lane produces: hid = 32w + 16nt + 4g + r
    float b1v[2][4];
#pragma unroll
    for (int nt = 0; nt < 2; ++nt)
#pragma unroll
        for (int r = 0; r < 4; ++r)
            b1v[nt][r] = b1[32 * w + 16 * nt + 4 * g + r];

    const int ecol = tid & 15;
    const float b2c = b2[ecol], gc = gamma[ecol], btc = beta[ecol];

    float esl = 0.f;
    const int base = blockIdx.x * 800;  // 2000 blocks * 25 iters * 32 edges

#pragma unroll 1
    for (int i = 0; i < 25; ++i) {
        const int ebase = base + i * 32;
        const int e0 = ebase + c, e1 = ebase + 16 + c;
        const size_t s0 = src[e0], s1 = src[e1];
        const size_t d0v = dst[e0], d1v = dst[e1];

        f32x4 acc[2][2];
#pragma unroll
        for (int t = 0; t < 2; ++t)
#pragma unroll
            for (int nt = 0; nt < 2; ++nt) {
                f32x4 z = {0.f, 0.f, 0.f, 0.f};
                acc[t][nt] = z;
            }

#pragma unroll
        for (int t = 0; t < 2; ++t) {
            const int et = (t ? e1 : e0);
            const size_t st = (t ? s1 : s0);
            const size_t dt = (t ? d1v : d0v);

            {   // kk=0: g<2 -> ea[e][8g] (runtime split), g>=2 -> xs plane
                bf16x8 eah, eal;
                ld8split(ea + (size_t)et * 16 + off8, 1.f, eah, eal);
                bf16x8 sh = *reinterpret_cast<const bf16x8*>(xh + st * 32 + off8);
                bf16x8 sl = *reinterpret_cast<const bf16x8*>(xl + st * 32 + off8);
                bf16x8 bh = glt2 ? eah : sh;
                bf16x8 bl = glt2 ? eal : sl;
                MFMA3(acc[t][0], w1h[0][0], w1l[0][0], bh, bl);
                MFMA3(acc[t][1], w1h[0][1], w1l[0][1], bh, bl);
            }
            {   // kk=1: g<2 -> xs[16+8g], g>=2 -> xd[8(g-2)] (planes only)
                const size_t row = glt2 ? st : dt;
                const int off = glt2 ? (16 + off8) : off8;
                bf16x8 bh = *reinterpret_cast<const bf16x8*>(xh + row * 32 + off);
                bf16x8 bl = *reinterpret_cast<const bf16x8*>(xl + row * 32 + off);
                MFMA3(acc[t][0], w1h[1][0], w1l[1][0], bh, bl);
                MFMA3(acc[t][1], w1h[1][1], w1l[1][1], bh, bl);
            }
            {   // kk=2: g<2 -> xd[16+8g] (plane), g>=2 -> u (hoisted)
                bf16x8 dh = *reinterpret_cast<const bf16x8*>(xh + dt * 32 + 16 + off8);
                bf16x8 dl = *reinterpret_cast<const bf16x8*>(xl + dt * 32 + 16 + off8);
                bf16x8 bh = glt2 ? dh : uh;
                bf16x8 bl = glt2 ? dl : ul;
                MFMA3(acc[t][0], w1h[2][0], w1l[2][0], bh, bl);
                MFMA3(acc[t][1], w1h[2][1], w1l[2][1], bh, bl);
            }
        }

        // ---- bias + ReLU + hi/lo split -> per-wave slab (swizzled)
#pragma unroll
        for (int t = 0; t < 2; ++t)
#pragma unroll
            for (int nt = 0; nt < 2; ++nt) {
                short4 hi4, lo4;
                float v0 = fmaxf(acc[t][nt][0] + b1v[nt][0], 0.f);
                float v1 = fmaxf(acc[t][nt][1] + b1v[nt][1], 0.f);
                float v2 = fmaxf(acc[t][nt][2] + b1v[nt][2], 0.f);
                float v3 = fmaxf(acc[t][nt][3] + b1v[nt][3], 0.f);
                splitf(v0, hi4.x, lo4.x); splitf(v1, hi4.y, lo4.y);
                splitf(v2, hi4.z, lo4.z); splitf(v3, hi4.w, lo4.w);
                const int grp = ((2 * nt + (g >> 1)) ^ csw) * 8 + 4 * (g & 1);
                *reinterpret_cast<short4*>(&hs[w][16 * t + c][0][grp]) = hi4;
                *reinterpret_cast<short4*>(&hs[w][16 * t + c][1][grp]) = lo4;
            }

        // ---- layer 2 (this wave's K=32 slice), split product
        f32x4 acc2[2];
#pragma unroll
        for (int t = 0; t < 2; ++t) { f32x4 z = {0.f, 0.f, 0.f, 0.f}; acc2[t] = z; }
#pragma unroll
        for (int t = 0; t < 2; ++t) {
            const int rg = (g ^ csw) * 8;
            bf16x8 a2h = *reinterpret_cast<const bf16x8*>(&hs[w][16 * t + c][0][rg]);
            bf16x8 a2l = *reinterpret_cast<const bf16x8*>(&hs[w][16 * t + c][1][rg]);
            acc2[t] = __builtin_amdgcn_mfma_f32_16x16x32_bf16(a2h, w2h, acc2[t], 0, 0, 0);
            acc2[t] = __builtin_amdgcn_mfma_f32_16x16x32_bf16(a2l, w2h, acc2[t], 0, 0, 0);
            acc2[t] = __builtin_amdgcn_mfma_f32_16x16x32_bf16(a2h, w2l, acc2[t], 0, 0, 0);
        }

        // ---- cross-wave partial reduce (dbuf; one barrier per iter)
        const int ib = i & 1;
#pragma unroll
        for (int t = 0; t < 2; ++t)
#pragma unroll
            for (int r = 0; r < 4; ++r)
                red[ib][w][16 * t + 4 * g + r][c] = acc2[t][r];
        __syncthreads();

        // ---- epilogue: 256 threads x 2 rows; bias, ReLU, LN(16), stores
#pragma unroll
        for (int pass = 0; pass < 2; ++pass) {
            const int erow = (tid >> 4) + 16 * pass;  // 0..31
            float o = red[ib][0][erow][ecol] + red[ib][1][erow][ecol] +
                      red[ib][2][erow][ecol] + red[ib][3][erow][ecol] + b2c;
            o = fmaxf(o, 0.f);
            float s = o, q = o * o;
            s += __shfl_xor(s, 1);  q += __shfl_xor(q, 1);
            s += __shfl_xor(s, 2);  q += __shfl_xor(q, 2);
            s += __shfl_xor(s, 4);  q += __shfl_xor(q, 4);
            s += __shfl_xor(s, 8);  q += __shfl_xor(q, 8);
            const float mu = s * 0.0625f;
            const float var = fmaxf(q * 0.0625f - mu * mu, 0.f);
            const float val = (o - mu) * rsqrtf(var + EPS_C) * gc + btc;
            const int e2 = ebase + erow;
            e_out[(size_t)e2 * 16 + ecol] = val;
            const int d2 = dst[e2];
            atomicAdd(&agg[(size_t)d2 * 16 + ecol], val);
            if (ecol == 0) atomicAdd(&cnt[d2], 1.f);
            esl += val;
        }
    }

    // ---- fused e_out column-sum
    esl += __shfl_xor(esl, 16);
    esl += __shfl_xor(esl, 32);
    if (l < 16) esr[w][c] = esl;
    __syncthreads();
    if (tid < 16) atomicAdd(&esum[tid], esr[0][tid] + esr[1][tid] + esr[2][tid] + esr[3][tid]);
}

// ===========================================================================
// Node MLP (unchanged from R3 — validated). in[64]=[x(32), agg*rcp(16), u(16)]
// ===========================================================================
__global__ __launch_bounds__(256, 1) void node_kernel(
    const float* __restrict__ x, const float* __restrict__ u,
    const float* __restrict__ W1, const float* __restrict__ b1,
    const float* __restrict__ W2, const float* __restrict__ b2,
    const float* __restrict__ gamma, const float* __restrict__ beta,
    const float* __restrict__ agg, const float* __restrict__ cnt,
    float* __restrict__ x_out, float* __restrict__ xsum)
{
    __shared__ __attribute__((aligned(16))) unsigned short hs[4][32][2][40];
    __shared__ float red[4][32][36];
    __shared__ float xsr[4][32];

    const int tid = threadIdx.x;
    const int w = tid >> 6, l = tid & 63, g = l >> 4, c = l & 15;
    const int csw = c >> 2;

    bf16x8 w1h[2][2], w1l[2][2];
#pragma unroll
    for (int kk = 0; kk < 2; ++kk)
#pragma unroll
        for (int nt = 0; nt < 2; ++nt) {
            bf16x8 h, lo;
#pragma unroll
            for (int j = 0; j < 8; ++j) {
                float f = W1[(size_t)(32 * kk + 8 * g + j) * 128 + 32 * w + 16 * nt + c];
                short sh, sl; splitf(f, sh, sl);
                h[j] = sh; lo[j] = sl;
            }
            w1h[kk][nt] = h; w1l[kk][nt] = lo;
        }

    bf16x8 w2h[2], w2l[2];
#pragma unroll
    for (int n2 = 0; n2 < 2; ++n2) {
        bf16x8 h, lo;
#pragma unroll
        for (int j = 0; j < 8; ++j) {
            float f = W2[(size_t)(32 * w + 8 * g + j) * 32 + 16 * n2 + c];
            short sh, sl; splitf(f, sh, sl);
            h[j] = sh; lo[j] = sl;
        }
        w2h[n2] = h; w2l[n2] = lo;
    }

    float b1v[2][4];
#pragma unroll
    for (int nt = 0; nt < 2; ++nt)
#pragma unroll
        for (int r = 0; r < 4; ++r)
            b1v[nt][r] = b1[32 * w + 16 * nt + 4 * g + r];

    const int ncol = tid & 31;
    const float b2c = b2[ncol], gc = gamma[ncol], btc = beta[ncol];

    const int nbase = blockIdx.x * 32;
    const int n0 = min(nbase + c, N_NODES_C - 1);
    const int n1 = min(nbase + 16 + c, N_NODES_C - 1);
    const float rcp0 = 1.f / fmaxf(cnt[n0], 1.f);
    const float rcp1 = 1.f / fmaxf(cnt[n1], 1.f);

    f32x4 acc[2][2];
#pragma unroll
    for (int t = 0; t < 2; ++t)
#pragma unroll
        for (int nt = 0; nt < 2; ++nt) {
            f32x4 z = {0.f, 0.f, 0.f, 0.f};
            acc[t][nt] = z;
        }

    {
        bf16x8 bh0, bl0, bh1, bl1;
        ld8split(x + (size_t)n0 * 32 + 8 * g, 1.f, bh0, bl0);
        ld8split(x + (size_t)n1 * 32 + 8 * g, 1.f, bh1, bl1);
#pragma unroll
        for (int nt = 0; nt < 2; ++nt) {
            MFMA3(acc[0][nt], w1h[0][nt], w1l[0][nt], bh0, bl0);
            MFMA3(acc[1][nt], w1h[0][nt], w1l[0][nt], bh1, bl1);
        }
    }
    {
        const float* p0 = (g < 2) ? (agg + (size_t)n0 * 16 + 8 * g) : (u + 8 * (g - 2));
        const float* p1 = (g < 2) ? (agg + (size_t)n1 * 16 + 8 * g) : (u + 8 * (g - 2));
        const float sc0 = (g < 2) ? rcp0 : 1.f;
        const float sc1 = (g < 2) ? rcp1 : 1.f;
        bf16x8 bh0, bl0, bh1, bl1;
        ld8split(p0, sc0, bh0, bl0); ld8split(p1, sc1, bh1, bl1);
#pragma unroll
        for (int nt = 0; nt < 2; ++nt) {
            MFMA3(acc[0][nt], w1h[1][nt], w1l[1][nt], bh0, bl0);
            MFMA3(acc[1][nt], w1h[1][nt], w1l[1][nt], bh1, bl1);
        }
    }

#pragma unroll
    for (int t = 0; t < 2; ++t)
#pragma unroll
        for (int nt = 0; nt < 2; ++nt) {
            short4 hi4, lo4;
            float v0 = fmaxf(acc[t][nt][0] + b1v[nt][0], 0.f);
            float v1 = fmaxf(acc[t][nt][1] + b1v[nt][1], 0.f);
            float v2 = fmaxf(acc[t][nt][2] + b1v[nt][2], 0.f);
            float v3 = fmaxf(acc[t][nt][3] + b1v[nt][3], 0.f);
            splitf(v0, hi4.x, lo4.x); splitf(v1, hi4.y, lo4.y);
            splitf(v2, hi4.z, lo4.z); splitf(v3, hi4.w, lo4.w);
            const int grp = ((2 * nt + (g >> 1)) ^ csw) * 8 + 4 * (g & 1);
            *reinterpret_cast<short4*>(&hs[w][16 * t + c][0][grp]) = hi4;
            *reinterpret_cast<short4*>(&hs[w][16 * t + c][1][grp]) = lo4;
        }

    f32x4 acc2[2][2];
#pragma unroll
    for (int t = 0; t < 2; ++t)
#pragma unroll
        for (int n2 = 0; n2 < 2; ++n2) {
            f32x4 z = {0.f, 0.f, 0.f, 0.f};
            acc2[t][n2] = z;
        }
#pragma unroll
    for (int t = 0; t < 2; ++t) {
        const int rg = (g ^ csw) * 8;
        bf16x8 a2h = *reinterpret_cast<const bf16x8*>(&hs[w][16 * t + c][0][rg]);
        bf16x8 a2l = *reinterpret_cast<const bf16x8*>(&hs[w][16 * t + c][1][rg]);
#pragma unroll
        for (int n2 = 0; n2 < 2; ++n2) {
            acc2[t][n2] = __builtin_amdgcn_mfma_f32_16x16x32_bf16(a2h, w2h[n2], acc2[t][n2], 0, 0, 0);
            acc2[t][n2] = __builtin_amdgcn_mfma_f32_16x16x32_bf16(a2l, w2h[n2], acc2[t][n2], 0, 0, 0);
            acc2[t][n2] = __builtin_amdgcn_mfma_f32_16x16x32_bf16(a2h, w2l[n2], acc2[t][n2], 0, 0, 0);
        }
    }

#pragma unroll
    for (int t = 0; t < 2; ++t)
#pragma unroll
        for (int n2 = 0; n2 < 2; ++n2)
#pragma unroll
            for (int r = 0; r < 4; ++r)
                red[w][16 * t + 4 * g + r][16 * n2 + c] = acc2[t][n2][r];
    __syncthreads();

    float xsl = 0.f;
#pragma unroll
    for (int pass = 0; pass < 4; ++pass) {
        const int nrow = (tid >> 5) + 8 * pass;
        float o = red[0][nrow][ncol] + red[1][nrow][ncol] +
                  red[2][nrow][ncol] + red[3][nrow][ncol] + b2c;
        o = fmaxf(o, 0.f);
        float s = o, q = o * o;
        s += __shfl_xor(s, 1);   q += __shfl_xor(q, 1);
        s += __shfl_xor(s, 2);   q += __shfl_xor(q, 2);
        s += __shfl_xor(s, 4);   q += __shfl_xor(q, 4);
        s += __shfl_xor(s, 8);   q += __shfl_xor(q, 8);
        s += __shfl_xor(s, 16);  q += __shfl_xor(q, 16);
        const float mu = s * (1.f / 32.f);
        const float var = fmaxf(q * (1.f / 32.f) - mu * mu, 0.f);
        const float val = (o - mu) * rsqrtf(var + EPS_C) * gc + btc;
        const int node = nbase + nrow;
        if (node < N_NODES_C) {
            x_out[(size_t)node * 32 + ncol] = val;
            xsl += val;
        }
    }

    xsl += __shfl_xor(xsl, 32);
    if (l < 32) xsr[w][l] = xsl;
    __syncthreads();
    if (tid < 32) atomicAdd(&xsum[tid], xsr[0][tid] + xsr[1][tid] + xsr[2][tid] + xsr[3][tid]);
}

// ===========================================================================
// Global MLP (tiny, f32)
// ===========================================================================
__global__ __launch_bounds__(128) void global_kernel(
    const float* __restrict__ u,
    const float* __restrict__ W1, const float* __restrict__ b1,
    const float* __restrict__ W2, const float* __restrict__ b2,
    const float* __restrict__ esum, const float* __restrict__ xsum,
    float* __restrict__ u_out)
{
    __shared__ float gin[64];
    __shared__ float h[128];
    const int t = threadIdx.x;

    if (t < 16) gin[t] = u[t];
    else if (t < 48) gin[t] = xsum[t - 16] * (1.f / (float)N_NODES_C);
    else if (t < 64) gin[t] = esum[t - 48] * (1.f / (float)N_EDGES_C);
    __syncthreads();

    float hv = b1[t];
    for (int k = 0; k < 64; k++) hv = fmaf(gin[k], W1[(size_t)k * 128 + t], hv);
    h[t] = fmaxf(hv, 0.f);
    __syncthreads();

    if (t < 16) {
        float o = b2[t];
        for (int j = 0; j < 128; j++) o = fmaf(h[j], W2[(size_t)j * 16 + t], o);
        u_out[t] = fmaxf(o, 0.f);
    }
}

// ===========================================================================
extern "C" void kernel_launch(void* const* d_in, const int* in_sizes, int n_in,
                              void* d_out, int out_size, void* d_ws, size_t ws_size,
                              hipStream_t stream)
{
    const float* x    = (const float*)d_in[0];
    const float* ea   = (const float*)d_in[1];
    const float* u    = (const float*)d_in[2];
    const int*   src  = (const int*)d_in[3];
    const int*   dst  = (const int*)d_in[4];
    const float* eW1  = (const float*)d_in[5];
    const float* eb1  = (const float*)d_in[6];
    const float* eW2  = (const float*)d_in[7];
    const float* eb2  = (const float*)d_in[8];
    const float* eg   = (const float*)d_in[9];
    const float* ebt  = (const float*)d_in[10];
    const float* nW1  = (const float*)d_in[11];
    const float* nb1  = (const float*)d_in[12];
    const float* nW2  = (const float*)d_in[13];
    const float* nb2  = (const float*)d_in[14];
    const float* ng   = (const float*)d_in[15];
    const float* nbt  = (const float*)d_in[16];
    const float* gW1  = (const float*)d_in[17];
    const float* gb1  = (const float*)d_in[18];
    const float* gW2  = (const float*)d_in[19];
    const float* gb2  = (const float*)d_in[20];

    float* x_out = (float*)d_out;                              // 50000*32
    float* e_out = (float*)d_out + (size_t)N_NODES_C * 32;     // 1.6M*16
    float* u_out = e_out + (size_t)N_EDGES_C * 16;             // 16

    float* agg   = (float*)d_ws;                 // 800000 f
    float* cnt   = agg + 800000;                 // 50000 f
    float* esum  = cnt + 50000;                  // 16 f
    float* xsum  = esum + 16;                    // 32 f
    unsigned short* xh = (unsigned short*)(xsum + 32);   // 1.6M ushort (16B-aligned)
    unsigned short* xl = xh + (size_t)N_NODES_C * 32;    // 1.6M ushort

    hipMemsetAsync(d_ws, 0, (size_t)(800000 + 50000 + 48) * sizeof(float), stream);

    prep_x_kernel<<<(N_NODES_C * 32 / 4 + 255) / 256, 256, 0, stream>>>(x, xh, xl);

    edge_kernel<<<2000, 256, 0, stream>>>(
        xh, xl, ea, u, src, dst, eW1, eb1, eW2, eb2, eg, ebt, e_out, agg, cnt, esum);

    node_kernel<<<(N_NODES_C + 31) / 32, 256, 0, stream>>>(
        x, u, nW1, nb1, nW2, nb2, ng, nbt, agg, cnt, x_out, xsum);

    global_kernel<<<1, 128, 0, stream>>>(
        u, gW1, gb1, gW2, gb2, esum, xsum, u_out);
}

// Round 5
// 738.682 us; speedup vs baseline: 1.4405x; 1.4405x over previous
//
#include <hip/hip_runtime.h>

#define N_NODES_C 50000
#define N_EDGES_C 1600000
#define EPS_C 1e-5f

typedef __attribute__((ext_vector_type(8))) short bf16x8;
typedef __attribute__((ext_vector_type(4))) float f32x4;

static __device__ __forceinline__ unsigned short rne_bf(float f) {
    union { float f; unsigned int u; } v; v.f = f;
    unsigned int r = v.u + 0x7fffu + ((v.u >> 16) & 1u);  // RNE
    return (unsigned short)(r >> 16);
}
static __device__ __forceinline__ float bf2f(unsigned short h) {
    union { unsigned int u; float f; } v; v.u = ((unsigned int)h) << 16;
    return v.f;
}
static __device__ __forceinline__ void splitf(float x, short& hi, short& lo) {
    unsigned short h = rne_bf(x);
    hi = (short)h;
    lo = (short)rne_bf(x - bf2f(h));
}
static __device__ __forceinline__ void ld8split(const float* p, float scale,
                                                bf16x8& hi, bf16x8& lo) {
    float4 a = *reinterpret_cast<const float4*>(p);
    float4 b = *reinterpret_cast<const float4*>(p + 4);
    float v[8] = {a.x, a.y, a.z, a.w, b.x, b.y, b.z, b.w};
#pragma unroll
    for (int i = 0; i < 8; ++i) {
        short h, l;
        splitf(v[i] * scale, h, l);
        hi[i] = h; lo[i] = l;
    }
}

// 3-term split product: acc += (Ah+Al)@(Bh+Bl) minus lo@lo
#define MFMA3(acc, wh, wl, bh, bl)                                            \
    acc = __builtin_amdgcn_mfma_f32_16x16x32_bf16(wh, bh, acc, 0, 0, 0);      \
    acc = __builtin_amdgcn_mfma_f32_16x16x32_bf16(wl, bh, acc, 0, 0, 0);      \
    acc = __builtin_amdgcn_mfma_f32_16x16x32_bf16(wh, bl, acc, 0, 0, 0);

// ===========================================================================
// CSR build: degree histogram
// ===========================================================================
__global__ __launch_bounds__(256) void deg_kernel(
    const int* __restrict__ dst, int* __restrict__ deg)
{
    const int e = blockIdx.x * 256 + threadIdx.x;
    if (e < N_EDGES_C) atomicAdd(&deg[dst[e]], 1);
}

// ===========================================================================
// Single-block exclusive scan over 50000 degrees -> rowstart; also cntf.
// Thread t serially owns chunk [t*49, t*49+49): sum, block-scan totals, emit.
// ===========================================================================
__global__ __launch_bounds__(1024) void scan_kernel(
    const int* __restrict__ deg, int* __restrict__ rowstart,
    float* __restrict__ cntf)
{
    const int C = 49;  // 1024*49 >= 50000
    __shared__ int tot[1024];
    const int t = threadIdx.x;
    const int beg = t * C;

    int sum = 0;
    for (int j = 0; j < C; ++j) {
        const int idx = beg + j;
        sum += (idx < N_NODES_C) ? deg[idx] : 0;
    }
    tot[t] = sum;
    __syncthreads();
    for (int off = 1; off < 1024; off <<= 1) {
        const int add = (t >= off) ? tot[t - off] : 0;
        __syncthreads();
        tot[t] += add;
        __syncthreads();
    }
    int run = tot[t] - sum;  // exclusive prefix of this chunk
    for (int j = 0; j < C; ++j) {
        const int idx = beg + j;
        if (idx < N_NODES_C) {
            const int v = deg[idx];
            rowstart[idx] = run;
            cntf[idx] = (float)v;
            run += v;
        }
    }
}

// ===========================================================================
// CSR fill: slot edges into per-node lists
// ===========================================================================
__global__ __launch_bounds__(256) void fill_kernel(
    const int* __restrict__ dst, const int* __restrict__ rowstart,
    int* __restrict__ cursor, int* __restrict__ eidx)
{
    const int e = blockIdx.x * 256 + threadIdx.x;
    if (e >= N_EDGES_C) return;
    const int d = dst[e];
    const int ofs = atomicAdd(&cursor[d], 1);
    eidx[rowstart[d] + ofs] = e;
}

// ===========================================================================
// Gather-aggregate: agg[n][c] = sum over incoming edges of e_out[e][c].
// 16 groups of 16 lanes per block; each group owns one node.
// Each e_out row (64 B aligned) is read exactly once device-wide.
// ===========================================================================
__global__ __launch_bounds__(256) void agg_kernel(
    const float* __restrict__ e_out, const int* __restrict__ eidx,
    const int* __restrict__ rowstart, const int* __restrict__ deg,
    float* __restrict__ agg)
{
    const int grp = threadIdx.x >> 4, col = threadIdx.x & 15;
    const int n = blockIdx.x * 16 + grp;
    if (n >= N_NODES_C) return;
    const int base = rowstart[n], d = deg[n];
    float acc = 0.f;
    for (int j = 0; j < d; ++j) {
        const int e = eidx[base + j];
        acc += e_out[(size_t)e * 16 + col];
    }
    agg[(size_t)n * 16 + col] = acc;
}

// ===========================================================================
// Edge MLP (R3-validated structure), atomics removed. Hidden split across
// 4 waves; layer-1 as h^T = W1^T @ in^T; layer-2 K-split reduced via LDS.
// ===========================================================================
__global__ __launch_bounds__(256, 1) void edge_kernel(
    const float* __restrict__ x, const float* __restrict__ ea,
    const float* __restrict__ u, const int* __restrict__ src,
    const int* __restrict__ dst,
    const float* __restrict__ W1, const float* __restrict__ b1,
    const float* __restrict__ W2, const float* __restrict__ b2,
    const float* __restrict__ gamma, const float* __restrict__ beta,
    float* __restrict__ e_out, float* __restrict__ esum)
{
    // per-wave hidden slab: [wave][edge-row 32][hi/lo][k-local 32 pad 40]
    __shared__ __attribute__((aligned(16))) unsigned short hs[4][32][2][40];
    // cross-wave layer-2 partials, double-buffered (pad 17 -> 38.1 KB total)
    __shared__ float red[2][4][32][17];
    __shared__ float esr[4][16];

    const int tid = threadIdx.x;
    const int w = tid >> 6, l = tid & 63, g = l >> 4, c = l & 15;
    const int csw = c >> 2;

    // ---- W1 fragments (this wave's 2 hidden n-tiles), hi/lo, in registers
    bf16x8 w1h[3][2], w1l[3][2];
#pragma unroll
    for (int kk = 0; kk < 3; ++kk)
#pragma unroll
        for (int nt = 0; nt < 2; ++nt) {
            bf16x8 h, lo;
#pragma unroll
            for (int j = 0; j < 8; ++j) {
                float f = W1[(size_t)(32 * kk + 8 * g + j) * 128 + 32 * w + 16 * nt + c];
                short sh, sl; splitf(f, sh, sl);
                h[j] = sh; lo[j] = sl;
            }
            w1h[kk][nt] = h; w1l[kk][nt] = lo;
        }

    // ---- W2 slice fragments (K rows [32w,32w+32)), hi/lo
    bf16x8 w2h, w2l;
    {
        bf16x8 h, lo;
#pragma unroll
        for (int j = 0; j < 8; ++j) {
            float f = W2[(size_t)(32 * w + 8 * g + j) * 16 + c];
            short sh, sl; splitf(f, sh, sl);
            h[j] = sh; lo[j] = sl;
        }
        w2h = h; w2l = lo;
    }

    // ---- b1 values this lane produces: hid = 32w + 16nt + 4g + r
    float b1v[2][4];
#pragma unroll
    for (int nt = 0; nt < 2; ++nt)
#pragma unroll
        for (int r = 0; r < 4; ++r)
            b1v[nt][r] = b1[32 * w + 16 * nt + 4 * g + r];

    const int ecol = tid & 15;
    const float b2c = b2[ecol], gc = gamma[ecol], btc = beta[ecol];

    float esl = 0.f;
    const int base = blockIdx.x * 800;  // 2000 blocks * 25 iters * 32 edges

#pragma unroll 1
    for (int i = 0; i < 25; ++i) {
        const int ebase = base + i * 32;
        const int e0 = ebase + c, e1 = ebase + 16 + c;
        const size_t s0 = src[e0], s1 = src[e1];
        const size_t d0v = dst[e0], d1v = dst[e1];

        f32x4 acc[2][2];
#pragma unroll
        for (int t = 0; t < 2; ++t)
#pragma unroll
            for (int nt = 0; nt < 2; ++nt) {
                f32x4 z = {0.f, 0.f, 0.f, 0.f};
                acc[t][nt] = z;
            }

#pragma unroll
        for (int t = 0; t < 2; ++t) {
            const int et = (t ? e1 : e0);
            const size_t st = (t ? s1 : s0);
            const size_t dt = (t ? d1v : d0v);

            {   // kk=0: g<2 -> ea[e][8g], g>=2 -> x[src][8(g-2)]
                const float* p = (g < 2) ? (ea + (size_t)et * 16 + 8 * g)
                                         : (x + st * 32 + 8 * (g - 2));
                bf16x8 bh, bl;
                ld8split(p, 1.f, bh, bl);
                MFMA3(acc[t][0], w1h[0][0], w1l[0][0], bh, bl);
                MFMA3(acc[t][1], w1h[0][1], w1l[0][1], bh, bl);
            }
            {   // kk=1: g<2 -> x[src][16+8g], g>=2 -> x[dst][8(g-2)]
                const float* p = (g < 2) ? (x + st * 32 + 16 + 8 * g)
                                         : (x + dt * 32 + 8 * (g - 2));
                bf16x8 bh, bl;
                ld8split(p, 1.f, bh, bl);
                MFMA3(acc[t][0], w1h[1][0], w1l[1][0], bh, bl);
                MFMA3(acc[t][1], w1h[1][1], w1l[1][1], bh, bl);
            }
            {   // kk=2: g<2 -> x[dst][16+8g], g>=2 -> u[8(g-2)]
                const float* p = (g < 2) ? (x + dt * 32 + 16 + 8 * g)
                                         : (u + 8 * (g - 2));
                bf16x8 bh, bl;
                ld8split(p, 1.f, bh, bl);
                MFMA3(acc[t][0], w1h[2][0], w1l[2][0], bh, bl);
                MFMA3(acc[t][1], w1h[2][1], w1l[2][1], bh, bl);
            }
        }

        // ---- bias + ReLU + hi/lo split -> per-wave slab (swizzled)
#pragma unroll
        for (int t = 0; t < 2; ++t)
#pragma unroll
            for (int nt = 0; nt < 2; ++nt) {
                short4 hi4, lo4;
                float v0 = fmaxf(acc[t][nt][0] + b1v[nt][0], 0.f);
                float v1 = fmaxf(acc[t][nt][1] + b1v[nt][1], 0.f);
                float v2 = fmaxf(acc[t][nt][2] + b1v[nt][2], 0.f);
                float v3 = fmaxf(acc[t][nt][3] + b1v[nt][3], 0.f);
                splitf(v0, hi4.x, lo4.x); splitf(v1, hi4.y, lo4.y);
                splitf(v2, hi4.z, lo4.z); splitf(v3, hi4.w, lo4.w);
                const int grp = ((2 * nt + (g >> 1)) ^ csw) * 8 + 4 * (g & 1);
                *reinterpret_cast<short4*>(&hs[w][16 * t + c][0][grp]) = hi4;
                *reinterpret_cast<short4*>(&hs[w][16 * t + c][1][grp]) = lo4;
            }

        // ---- layer 2 (this wave's K=32 slice), split product
        f32x4 acc2[2];
#pragma unroll
        for (int t = 0; t < 2; ++t) { f32x4 z = {0.f, 0.f, 0.f, 0.f}; acc2[t] = z; }
#pragma unroll
        for (int t = 0; t < 2; ++t) {
            const int rg = (g ^ csw) * 8;
            bf16x8 a2h = *reinterpret_cast<const bf16x8*>(&hs[w][16 * t + c][0][rg]);
            bf16x8 a2l = *reinterpret_cast<const bf16x8*>(&hs[w][16 * t + c][1][rg]);
            acc2[t] = __builtin_amdgcn_mfma_f32_16x16x32_bf16(a2h, w2h, acc2[t], 0, 0, 0);
            acc2[t] = __builtin_amdgcn_mfma_f32_16x16x32_bf16(a2l, w2h, acc2[t], 0, 0, 0);
            acc2[t] = __builtin_amdgcn_mfma_f32_16x16x32_bf16(a2h, w2l, acc2[t], 0, 0, 0);
        }

        // ---- cross-wave partial reduce (dbuf; one barrier per iter)
        const int ib = i & 1;
#pragma unroll
        for (int t = 0; t < 2; ++t)
#pragma unroll
            for (int r = 0; r < 4; ++r)
                red[ib][w][16 * t + 4 * g + r][c] = acc2[t][r];
        __syncthreads();

        // ---- epilogue: bias, ReLU, LN(16), coalesced e_out store (no atomics)
#pragma unroll
        for (int pass = 0; pass < 2; ++pass) {
            const int erow = (tid >> 4) + 16 * pass;  // 0..31
            float o = red[ib][0][erow][ecol] + red[ib][1][erow][ecol] +
                      red[ib][2][erow][ecol] + red[ib][3][erow][ecol] + b2c;
            o = fmaxf(o, 0.f);
            float s = o, q = o * o;
            s += __shfl_xor(s, 1);  q += __shfl_xor(q, 1);
            s += __shfl_xor(s, 2);  q += __shfl_xor(q, 2);
            s += __shfl_xor(s, 4);  q += __shfl_xor(q, 4);
            s += __shfl_xor(s, 8);  q += __shfl_xor(q, 8);
            const float mu = s * 0.0625f;
            const float var = fmaxf(q * 0.0625f - mu * mu, 0.f);
            const float val = (o - mu) * rsqrtf(var + EPS_C) * gc + btc;
            const int e2 = ebase + erow;
            e_out[(size_t)e2 * 16 + ecol] = val;
            esl += val;
        }
    }

    // ---- fused e_out column-sum
    esl += __shfl_xor(esl, 16);
    esl += __shfl_xor(esl, 32);
    if (l < 16) esr[w][c] = esl;
    __syncthreads();
    if (tid < 16) atomicAdd(&esum[tid], esr[0][tid] + esr[1][tid] + esr[2][tid] + esr[3][tid]);
}

// ===========================================================================
// Node MLP (unchanged, validated). in[64]=[x(32), agg*rcp(16), u(16)]
// ===========================================================================
__global__ __launch_bounds__(256, 1) void node_kernel(
    const float* __restrict__ x, const float* __restrict__ u,
    const float* __restrict__ W1, const float* __restrict__ b1,
    const float* __restrict__ W2, const float* __restrict__ b2,
    const float* __restrict__ gamma, const float* __restrict__ beta,
    const float* __restrict__ agg, const float* __restrict__ cnt,
    float* __restrict__ x_out, float* __restrict__ xsum)
{
    __shared__ __attribute__((aligned(16))) unsigned short hs[4][32][2][40];
    __shared__ float red[4][32][36];
    __shared__ float xsr[4][32];

    const int tid = threadIdx.x;
    const int w = tid >> 6, l = tid & 63, g = l >> 4, c = l & 15;
    const int csw = c >> 2;

    bf16x8 w1h[2][2], w1l[2][2];
#pragma unroll
    for (int kk = 0; kk < 2; ++kk)
#pragma unroll
        for (int nt = 0; nt < 2; ++nt) {
            bf16x8 h, lo;
#pragma unroll
            for (int j = 0; j < 8; ++j) {
                float f = W1[(size_t)(32 * kk + 8 * g + j) * 128 + 32 * w + 16 * nt + c];
                short sh, sl; splitf(f, sh, sl);
                h[j] = sh; lo[j] = sl;
            }
            w1h[kk][nt] = h; w1l[kk][nt] = lo;
        }

    bf16x8 w2h[2], w2l[2];
#pragma unroll
    for (int n2 = 0; n2 < 2; ++n2) {
        bf16x8 h, lo;
#pragma unroll
        for (int j = 0; j < 8; ++j) {
            float f = W2[(size_t)(32 * w + 8 * g + j) * 32 + 16 * n2 + c];
            short sh, sl; splitf(f, sh, sl);
            h[j] = sh; lo[j] = sl;
        }
        w2h[n2] = h; w2l[n2] = lo;
    }

    float b1v[2][4];
#pragma unroll
    for (int nt = 0; nt < 2; ++nt)
#pragma unroll
        for (int r = 0; r < 4; ++r)
            b1v[nt][r] = b1[32 * w + 16 * nt + 4 * g + r];

    const int ncol = tid & 31;
    const float b2c = b2[ncol], gc = gamma[ncol], btc = beta[ncol];

    const int nbase = blockIdx.x * 32;
    const int n0 = min(nbase + c, N_NODES_C - 1);
    const int n1 = min(nbase + 16 + c, N_NODES_C - 1);
    const float rcp0 = 1.f / fmaxf(cnt[n0], 1.f);
    const float rcp1 = 1.f / fmaxf(cnt[n1], 1.f);

    f32x4 acc[2][2];
#pragma unroll
    for (int t = 0; t < 2; ++t)
#pragma unroll
        for (int nt = 0; nt < 2; ++nt) {
            f32x4 z = {0.f, 0.f, 0.f, 0.f};
            acc[t][nt] = z;
        }

    {
        bf16x8 bh0, bl0, bh1, bl1;
        ld8split(x + (size_t)n0 * 32 + 8 * g, 1.f, bh0, bl0);
        ld8split(x + (size_t)n1 * 32 + 8 * g, 1.f, bh1, bl1);
#pragma unroll
        for (int nt = 0; nt < 2; ++nt) {
            MFMA3(acc[0][nt], w1h[0][nt], w1l[0][nt], bh0, bl0);
            MFMA3(acc[1][nt], w1h[0][nt], w1l[0][nt], bh1, bl1);
        }
    }
    {
        const float* p0 = (g < 2) ? (agg + (size_t)n0 * 16 + 8 * g) : (u + 8 * (g - 2));
        const float* p1 = (g < 2) ? (agg + (size_t)n1 * 16 + 8 * g) : (u + 8 * (g - 2));
        const float sc0 = (g < 2) ? rcp0 : 1.f;
        const float sc1 = (g < 2) ? rcp1 : 1.f;
        bf16x8 bh0, bl0, bh1, bl1;
        ld8split(p0, sc0, bh0, bl0); ld8split(p1, sc1, bh1, bl1);
#pragma unroll
        for (int nt = 0; nt < 2; ++nt) {
            MFMA3(acc[0][nt], w1h[1][nt], w1l[1][nt], bh0, bl0);
            MFMA3(acc[1][nt], w1h[1][nt], w1l[1][nt], bh1, bl1);
        }
    }

#pragma unroll
    for (int t = 0; t < 2; ++t)
#pragma unroll
        for (int nt = 0; nt < 2; ++nt) {
            short4 hi4, lo4;
            float v0 = fmaxf(acc[t][nt][0] + b1v[nt][0], 0.f);
            float v1 = fmaxf(acc[t][nt][1] + b1v[nt][1], 0.f);
            float v2 = fmaxf(acc[t][nt][2] + b1v[nt][2], 0.f);
            float v3 = fmaxf(acc[t][nt][3] + b1v[nt][3], 0.f);
            splitf(v0, hi4.x, lo4.x); splitf(v1, hi4.y, lo4.y);
            splitf(v2, hi4.z, lo4.z); splitf(v3, hi4.w, lo4.w);
            const int grp = ((2 * nt + (g >> 1)) ^ csw) * 8 + 4 * (g & 1);
            *reinterpret_cast<short4*>(&hs[w][16 * t + c][0][grp]) = hi4;
            *reinterpret_cast<short4*>(&hs[w][16 * t + c][1][grp]) = lo4;
        }

    f32x4 acc2[2][2];
#pragma unroll
    for (int t = 0; t < 2; ++t)
#pragma unroll
        for (int n2 = 0; n2 < 2; ++n2) {
            f32x4 z = {0.f, 0.f, 0.f, 0.f};
            acc2[t][n2] = z;
        }
#pragma unroll
    for (int t = 0; t < 2; ++t) {
        const int rg = (g ^ csw) * 8;
        bf16x8 a2h = *reinterpret_cast<const bf16x8*>(&hs[w][16 * t + c][0][rg]);
        bf16x8 a2l = *reinterpret_cast<const bf16x8*>(&hs[w][16 * t + c][1][rg]);
#pragma unroll
        for (int n2 = 0; n2 < 2; ++n2) {
            acc2[t][n2] = __builtin_amdgcn_mfma_f32_16x16x32_bf16(a2h, w2h[n2], acc2[t][n2], 0, 0, 0);
            acc2[t][n2] = __builtin_amdgcn_mfma_f32_16x16x32_bf16(a2l, w2h[n2], acc2[t][n2], 0, 0, 0);
            acc2[t][n2] = __builtin_amdgcn_mfma_f32_16x16x32_bf16(a2h, w2l[n2], acc2[t][n2], 0, 0, 0);
        }
    }

#pragma unroll
    for (int t = 0; t < 2; ++t)
#pragma unroll
        for (int n2 = 0; n2 < 2; ++n2)
#pragma unroll
            for (int r = 0; r < 4; ++r)
                red[w][16 * t + 4 * g + r][16 * n2 + c] = acc2[t][n2][r];
    __syncthreads();

    float xsl = 0.f;
#pragma unroll
    for (int pass = 0; pass < 4; ++pass) {
        const int nrow = (tid >> 5) + 8 * pass;
        float o = red[0][nrow][ncol] + red[1][nrow][ncol] +
                  red[2][nrow][ncol] + red[3][nrow][ncol] + b2c;
        o = fmaxf(o, 0.f);
        float s = o, q = o * o;
        s += __shfl_xor(s, 1);   q += __shfl_xor(q, 1);
        s += __shfl_xor(s, 2);   q += __shfl_xor(q, 2);
        s += __shfl_xor(s, 4);   q += __shfl_xor(q, 4);
        s += __shfl_xor(s, 8);   q += __shfl_xor(q, 8);
        s += __shfl_xor(s, 16);  q += __shfl_xor(q, 16);
        const float mu = s * (1.f / 32.f);
        const float var = fmaxf(q * (1.f / 32.f) - mu * mu, 0.f);
        const float val = (o - mu) * rsqrtf(var + EPS_C) * gc + btc;
        const int node = nbase + nrow;
        if (node < N_NODES_C) {
            x_out[(size_t)node * 32 + ncol] = val;
            xsl += val;
        }
    }

    xsl += __shfl_xor(xsl, 32);
    if (l < 32) xsr[w][l] = xsl;
    __syncthreads();
    if (tid < 32) atomicAdd(&xsum[tid], xsr[0][tid] + xsr[1][tid] + xsr[2][tid] + xsr[3][tid]);
}

// ===========================================================================
// Global MLP (tiny, f32)
// ===========================================================================
__global__ __launch_bounds__(128) void global_kernel(
    const float* __restrict__ u,
    const float* __restrict__ W1, const float* __restrict__ b1,
    const float* __restrict__ W2, const float* __restrict__ b2,
    const float* __restrict__ esum, const float* __restrict__ xsum,
    float* __restrict__ u_out)
{
    __shared__ float gin[64];
    __shared__ float h[128];
    const int t = threadIdx.x;

    if (t < 16) gin[t] = u[t];
    else if (t < 48) gin[t] = xsum[t - 16] * (1.f / (float)N_NODES_C);
    else if (t < 64) gin[t] = esum[t - 48] * (1.f / (float)N_EDGES_C);
    __syncthreads();

    float hv = b1[t];
    for (int k = 0; k < 64; k++) hv = fmaf(gin[k], W1[(size_t)k * 128 + t], hv);
    h[t] = fmaxf(hv, 0.f);
    __syncthreads();

    if (t < 16) {
        float o = b2[t];
        for (int j = 0; j < 128; j++) o = fmaf(h[j], W2[(size_t)j * 16 + t], o);
        u_out[t] = fmaxf(o, 0.f);
    }
}

// ===========================================================================
extern "C" void kernel_launch(void* const* d_in, const int* in_sizes, int n_in,
                              void* d_out, int out_size, void* d_ws, size_t ws_size,
                              hipStream_t stream)
{
    const float* x    = (const float*)d_in[0];
    const float* ea   = (const float*)d_in[1];
    const float* u    = (const float*)d_in[2];
    const int*   src  = (const int*)d_in[3];
    const int*   dst  = (const int*)d_in[4];
    const float* eW1  = (const float*)d_in[5];
    const float* eb1  = (const float*)d_in[6];
    const float* eW2  = (const float*)d_in[7];
    const float* eb2  = (const float*)d_in[8];
    const float* eg   = (const float*)d_in[9];
    const float* ebt  = (const float*)d_in[10];
    const float* nW1  = (const float*)d_in[11];
    const float* nb1  = (const float*)d_in[12];
    const float* nW2  = (const float*)d_in[13];
    const float* nb2  = (const float*)d_in[14];
    const float* ng   = (const float*)d_in[15];
    const float* nbt  = (const float*)d_in[16];
    const float* gW1  = (const float*)d_in[17];
    const float* gb1  = (const float*)d_in[18];
    const float* gW2  = (const float*)d_in[19];
    const float* gb2  = (const float*)d_in[20];

    float* x_out = (float*)d_out;                              // 50000*32
    float* e_out = (float*)d_out + (size_t)N_NODES_C * 32;     // 1.6M*16
    float* u_out = e_out + (size_t)N_EDGES_C * 16;             // 16

    // ws layout
    float* agg      = (float*)d_ws;              // 800000 f  (fully overwritten)
    float* cntf     = agg + 800000;              // 50000 f   (written by scan)
    float* esum     = cntf + 50000;              // 16 f      (memset)
    float* xsum     = esum + 16;                 // 32 f      (memset)
    int*   deg      = (int*)(xsum + 32);         // 50000     (memset)
    int*   cursor   = deg + 50000;               // 50000     (memset)
    int*   rowstart = cursor + 50000;            // 50000     (written by scan)
    int*   eidx     = rowstart + 50000;          // 1600000   (written by fill)

    // zero: esum, xsum, deg, cursor (contiguous)
    hipMemsetAsync(esum, 0, (size_t)(16 + 32 + 50000 + 50000) * sizeof(float), stream);

    edge_kernel<<<2000, 256, 0, stream>>>(
        x, ea, u, src, dst, eW1, eb1, eW2, eb2, eg, ebt, e_out, esum);

    deg_kernel<<<(N_EDGES_C + 255) / 256, 256, 0, stream>>>(dst, deg);
    scan_kernel<<<1, 1024, 0, stream>>>(deg, rowstart, cntf);
    fill_kernel<<<(N_EDGES_C + 255) / 256, 256, 0, stream>>>(dst, rowstart, cursor, eidx);
    agg_kernel<<<(N_NODES_C + 15) / 16, 256, 0, stream>>>(e_out, eidx, rowstart, deg, agg);

    node_kernel<<<(N_NODES_C + 31) / 32, 256, 0, stream>>>(
        x, u, nW1, nb1, nW2, nb2, ng, nbt, agg, cntf, x_out, xsum);

    global_kernel<<<1, 128, 0, stream>>>(
        u, gW1, gb1, gW2, gb2, esum, xsum, u_out);
}

// Round 6
// 428.358 us; speedup vs baseline: 2.4841x; 1.7244x over previous
//
#include <hip/hip_runtime.h>

#define N_NODES_C 50000
#define N_EDGES_C 1600000
#define EPS_C 1e-5f

typedef __attribute__((ext_vector_type(8))) short bf16x8;
typedef __attribute__((ext_vector_type(4))) float f32x4;

static __device__ __forceinline__ unsigned short rne_bf(float f) {
    union { float f; unsigned int u; } v; v.f = f;
    unsigned int r = v.u + 0x7fffu + ((v.u >> 16) & 1u);  // RNE
    return (unsigned short)(r >> 16);
}
static __device__ __forceinline__ float bf2f(unsigned short h) {
    union { unsigned int u; float f; } v; v.u = ((unsigned int)h) << 16;
    return v.f;
}
static __device__ __forceinline__ void splitf(float x, short& hi, short& lo) {
    unsigned short h = rne_bf(x);
    hi = (short)h;
    lo = (short)rne_bf(x - bf2f(h));
}
static __device__ __forceinline__ void ld8split(const float* p, float scale,
                                                bf16x8& hi, bf16x8& lo) {
    float4 a = *reinterpret_cast<const float4*>(p);
    float4 b = *reinterpret_cast<const float4*>(p + 4);
    float v[8] = {a.x, a.y, a.z, a.w, b.x, b.y, b.z, b.w};
#pragma unroll
    for (int i = 0; i < 8; ++i) {
        short h, l;
        splitf(v[i] * scale, h, l);
        hi[i] = h; lo[i] = l;
    }
}

// 3-term split product: acc += (Ah+Al)@(Bh+Bl) minus lo@lo
#define MFMA3(acc, wh, wl, bh, bl)                                            \
    acc = __builtin_amdgcn_mfma_f32_16x16x32_bf16(wh, bh, acc, 0, 0, 0);      \
    acc = __builtin_amdgcn_mfma_f32_16x16x32_bf16(wl, bh, acc, 0, 0, 0);      \
    acc = __builtin_amdgcn_mfma_f32_16x16x32_bf16(wh, bl, acc, 0, 0, 0);

// ===========================================================================
// Pre-split x (50000x32 f32) into bf16 hi/lo planes.
// ===========================================================================
__global__ __launch_bounds__(256) void prep_x_kernel(
    const float* __restrict__ x,
    unsigned short* __restrict__ xh, unsigned short* __restrict__ xl)
{
    const int i = blockIdx.x * 256 + threadIdx.x;  // float4 index
    if (i >= (N_NODES_C * 32) / 4) return;
    float4 v = reinterpret_cast<const float4*>(x)[i];
    short4 h, l;
    splitf(v.x, h.x, l.x); splitf(v.y, h.y, l.y);
    splitf(v.z, h.z, l.z); splitf(v.w, h.w, l.w);
    reinterpret_cast<short4*>(xh)[i] = h;
    reinterpret_cast<short4*>(xl)[i] = l;
}

// ===========================================================================
// Fold the 8 XCD-local accumulator copies: agg = sum(agg8), cntf = sum(cnt8)
// ===========================================================================
__global__ __launch_bounds__(256) void reduce_kernel(
    const float* __restrict__ agg8, const float* __restrict__ cnt8,
    float* __restrict__ agg, float* __restrict__ cntf)
{
    const int i = blockIdx.x * 256 + threadIdx.x;
    if (i < N_NODES_C * 16) {
        float s = 0.f;
#pragma unroll
        for (int k = 0; k < 8; ++k) s += agg8[(size_t)k * (N_NODES_C * 16) + i];
        agg[i] = s;
    }
    if (i < N_NODES_C) {
        float s = 0.f;
#pragma unroll
        for (int k = 0; k < 8; ++k) s += cnt8[(size_t)k * N_NODES_C + i];
        cntf[i] = s;
    }
}

// ===========================================================================
// Edge MLP (R3-validated MFMA structure). K permuted to [ea(16),u(16),
// xs(32),xd(32)] so kk1/kk2 are pure pre-split plane loads; only ea is
// split in-loop (half-wave), u hoisted. Scatter atomics go to the
// blockIdx&7 XCD-local copy of agg/cnt.
// ===========================================================================
__global__ __launch_bounds__(256) void edge_kernel(
    const unsigned short* __restrict__ xh, const unsigned short* __restrict__ xl,
    const float* __restrict__ ea, const float* __restrict__ u,
    const int* __restrict__ src, const int* __restrict__ dst,
    const float* __restrict__ W1, const float* __restrict__ b1,
    const float* __restrict__ W2, const float* __restrict__ b2,
    const float* __restrict__ gamma, const float* __restrict__ beta,
    float* __restrict__ e_out, float* __restrict__ agg8, float* __restrict__ cnt8,
    float* __restrict__ esum)
{
    // per-wave hidden slab: [wave][edge-row 32][hi/lo][k-local 32 pad 40]
    __shared__ __attribute__((aligned(16))) unsigned short hs[4][32][2][40];
    // cross-wave layer-2 partials, double-buffered (pad 17)
    __shared__ float red[2][4][32][17];
    __shared__ float esr[4][16];

    const int tid = threadIdx.x;
    const int w = tid >> 6, l = tid & 63, g = l >> 4, c = l & 15;
    const int csw = c >> 2;
    const int off8 = 8 * (g & 1);

    // XCD-local accumulator copy
    float* aggc = agg8 + (size_t)(blockIdx.x & 7) * (N_NODES_C * 16);
    float* cntc = cnt8 + (size_t)(blockIdx.x & 7) * N_NODES_C;

    // ---- W1 fragments, K-permuted: kp -> orig row
    //      kp<16: ea (orig kp); kp<32: u (orig 80+kp-16);
    //      kp<64: xs (orig 16+kp-32); else xd (orig 48+kp-64)
    bf16x8 w1h[3][2], w1l[3][2];
#pragma unroll
    for (int kk = 0; kk < 3; ++kk)
#pragma unroll
        for (int nt = 0; nt < 2; ++nt) {
            bf16x8 h, lo;
#pragma unroll
            for (int j = 0; j < 8; ++j) {
                const int kp = 32 * kk + 8 * g + j;
                const int orig = (kp < 16) ? kp
                               : (kp < 32) ? (64 + kp)       // 80 + kp - 16
                               : (kp < 64) ? (kp - 16)       // 16 + kp - 32
                                           : (kp - 16);      // 48 + kp - 64
                float f = W1[(size_t)orig * 128 + 32 * w + 16 * nt + c];
                short sh, sl; splitf(f, sh, sl);
                h[j] = sh; lo[j] = sl;
            }
            w1h[kk][nt] = h; w1l[kk][nt] = lo;
        }

    // ---- W2 slice fragments (K rows [32w,32w+32)), hi/lo
    bf16x8 w2h, w2l;
    {
        bf16x8 h, lo;
#pragma unroll
        for (int j = 0; j < 8; ++j) {
            float f = W2[(size_t)(32 * w + 8 * g + j) * 16 + c];
            short sh, sl; splitf(f, sh, sl);
            h[j] = sh; lo[j] = sl;
        }
        w2h = h; w2l = lo;
    }

    // ---- hoisted u fragments (lanes g>=2 use u cols 8*(g-2) = off8)
    bf16x8 uh, ul;
    ld8split(u + off8, 1.f, uh, ul);

    // ---- b1 values this lane produces: hid = 32w + 16nt + 4g + r
    float b1v[2][4];
#pragma unroll
    for (int nt = 0; nt < 2; ++nt)
#pragma unroll
        for (int r = 0; r < 4; ++r)
            b1v[nt][r] = b1[32 * w + 16 * nt + 4 * g + r];

    const int ecol = tid & 15;
    const float b2c = b2[ecol], gc = gamma[ecol], btc = beta[ecol];

    float esl = 0.f;
    const int base = blockIdx.x * 800;  // 2000 blocks * 25 iters * 32 edges

#pragma unroll 1
    for (int i = 0; i < 25; ++i) {
        const int ebase = base + i * 32;
        const int e0 = ebase + c, e1 = ebase + 16 + c;
        const size_t s0 = src[e0], s1 = src[e1];
        const size_t d0v = dst[e0], d1v = dst[e1];

        f32x4 acc[2][2];
#pragma unroll
        for (int t = 0; t < 2; ++t)
#pragma unroll
            for (int nt = 0; nt < 2; ++nt) {
                f32x4 z = {0.f, 0.f, 0.f, 0.f};
                acc[t][nt] = z;
            }

#pragma unroll
        for (int t = 0; t < 2; ++t) {
            const int et = (t ? e1 : e0);
            const size_t st = (t ? s1 : s0);
            const size_t dt = (t ? d1v : d0v);

            {   // kk=0: g<2 -> ea[e][8g] (runtime split); g>=2 -> u (hoisted)
                bf16x8 bh, bl;
                if (g < 2) {
                    ld8split(ea + (size_t)et * 16 + off8, 1.f, bh, bl);
                } else {
                    bh = uh; bl = ul;
                }
                MFMA3(acc[t][0], w1h[0][0], w1l[0][0], bh, bl);
                MFMA3(acc[t][1], w1h[0][1], w1l[0][1], bh, bl);
            }
            {   // kk=1: xs plane cols 8g
                bf16x8 bh = *reinterpret_cast<const bf16x8*>(xh + st * 32 + 8 * g);
                bf16x8 bl = *reinterpret_cast<const bf16x8*>(xl + st * 32 + 8 * g);
                MFMA3(acc[t][0], w1h[1][0], w1l[1][0], bh, bl);
                MFMA3(acc[t][1], w1h[1][1], w1l[1][1], bh, bl);
            }
            {   // kk=2: xd plane cols 8g
                bf16x8 bh = *reinterpret_cast<const bf16x8*>(xh + dt * 32 + 8 * g);
                bf16x8 bl = *reinterpret_cast<const bf16x8*>(xl + dt * 32 + 8 * g);
                MFMA3(acc[t][0], w1h[2][0], w1l[2][0], bh, bl);
                MFMA3(acc[t][1], w1h[2][1], w1l[2][1], bh, bl);
            }
        }

        // ---- bias + ReLU + hi/lo split -> per-wave slab (swizzled)
#pragma unroll
        for (int t = 0; t < 2; ++t)
#pragma unroll
            for (int nt = 0; nt < 2; ++nt) {
                short4 hi4, lo4;
                float v0 = fmaxf(acc[t][nt][0] + b1v[nt][0], 0.f);
                float v1 = fmaxf(acc[t][nt][1] + b1v[nt][1], 0.f);
                float v2 = fmaxf(acc[t][nt][2] + b1v[nt][2], 0.f);
                float v3 = fmaxf(acc[t][nt][3] + b1v[nt][3], 0.f);
                splitf(v0, hi4.x, lo4.x); splitf(v1, hi4.y, lo4.y);
                splitf(v2, hi4.z, lo4.z); splitf(v3, hi4.w, lo4.w);
                const int grp = ((2 * nt + (g >> 1)) ^ csw) * 8 + 4 * (g & 1);
                *reinterpret_cast<short4*>(&hs[w][16 * t + c][0][grp]) = hi4;
                *reinterpret_cast<short4*>(&hs[w][16 * t + c][1][grp]) = lo4;
            }

        // ---- layer 2 (this wave's K=32 slice), split product
        f32x4 acc2[2];
#pragma unroll
        for (int t = 0; t < 2; ++t) { f32x4 z = {0.f, 0.f, 0.f, 0.f}; acc2[t] = z; }
#pragma unroll
        for (int t = 0; t < 2; ++t) {
            const int rg = (g ^ csw) * 8;
            bf16x8 a2h = *reinterpret_cast<const bf16x8*>(&hs[w][16 * t + c][0][rg]);
            bf16x8 a2l = *reinterpret_cast<const bf16x8*>(&hs[w][16 * t + c][1][rg]);
            acc2[t] = __builtin_amdgcn_mfma_f32_16x16x32_bf16(a2h, w2h, acc2[t], 0, 0, 0);
            acc2[t] = __builtin_amdgcn_mfma_f32_16x16x32_bf16(a2l, w2h, acc2[t], 0, 0, 0);
            acc2[t] = __builtin_amdgcn_mfma_f32_16x16x32_bf16(a2h, w2l, acc2[t], 0, 0, 0);
        }

        // ---- cross-wave partial reduce (dbuf; one barrier per iter)
        const int ib = i & 1;
#pragma unroll
        for (int t = 0; t < 2; ++t)
#pragma unroll
            for (int r = 0; r < 4; ++r)
                red[ib][w][16 * t + 4 * g + r][c] = acc2[t][r];
        __syncthreads();

        // ---- epilogue: bias, ReLU, LN(16), store + XCD-local scatter
#pragma unroll
        for (int pass = 0; pass < 2; ++pass) {
            const int erow = (tid >> 4) + 16 * pass;  // 0..31
            float o = red[ib][0][erow][ecol] + red[ib][1][erow][ecol] +
                      red[ib][2][erow][ecol] + red[ib][3][erow][ecol] + b2c;
            o = fmaxf(o, 0.f);
            float s = o, q = o * o;
            s += __shfl_xor(s, 1);  q += __shfl_xor(q, 1);
            s += __shfl_xor(s, 2);  q += __shfl_xor(q, 2);
            s += __shfl_xor(s, 4);  q += __shfl_xor(q, 4);
            s += __shfl_xor(s, 8);  q += __shfl_xor(q, 8);
            const float mu = s * 0.0625f;
            const float var = fmaxf(q * 0.0625f - mu * mu, 0.f);
            const float val = (o - mu) * rsqrtf(var + EPS_C) * gc + btc;
            const int e2 = ebase + erow;
            e_out[(size_t)e2 * 16 + ecol] = val;
            const int d2 = dst[e2];
            atomicAdd(&aggc[(size_t)d2 * 16 + ecol], val);
            if (ecol == 0) atomicAdd(&cntc[d2], 1.f);
            esl += val;
        }
    }

    // ---- fused e_out column-sum
    esl += __shfl_xor(esl, 16);
    esl += __shfl_xor(esl, 32);
    if (l < 16) esr[w][c] = esl;
    __syncthreads();
    if (tid < 16) atomicAdd(&esum[tid], esr[0][tid] + esr[1][tid] + esr[2][tid] + esr[3][tid]);
}

// ===========================================================================
// Node MLP (unchanged, validated). in[64]=[x(32), agg*rcp(16), u(16)]
// ===========================================================================
__global__ __launch_bounds__(256, 1) void node_kernel(
    const float* __restrict__ x, const float* __restrict__ u,
    const float* __restrict__ W1, const float* __restrict__ b1,
    const float* __restrict__ W2, const float* __restrict__ b2,
    const float* __restrict__ gamma, const float* __restrict__ beta,
    const float* __restrict__ agg, const float* __restrict__ cnt,
    float* __restrict__ x_out, float* __restrict__ xsum)
{
    __shared__ __attribute__((aligned(16))) unsigned short hs[4][32][2][40];
    __shared__ float red[4][32][36];
    __shared__ float xsr[4][32];

    const int tid = threadIdx.x;
    const int w = tid >> 6, l = tid & 63, g = l >> 4, c = l & 15;
    const int csw = c >> 2;

    bf16x8 w1h[2][2], w1l[2][2];
#pragma unroll
    for (int kk = 0; kk < 2; ++kk)
#pragma unroll
        for (int nt = 0; nt < 2; ++nt) {
            bf16x8 h, lo;
#pragma unroll
            for (int j = 0; j < 8; ++j) {
                float f = W1[(size_t)(32 * kk + 8 * g + j) * 128 + 32 * w + 16 * nt + c];
                short sh, sl; splitf(f, sh, sl);
                h[j] = sh; lo[j] = sl;
            }
            w1h[kk][nt] = h; w1l[kk][nt] = lo;
        }

    bf16x8 w2h[2], w2l[2];
#pragma unroll
    for (int n2 = 0; n2 < 2; ++n2) {
        bf16x8 h, lo;
#pragma unroll
        for (int j = 0; j < 8; ++j) {
            float f = W2[(size_t)(32 * w + 8 * g + j) * 32 + 16 * n2 + c];
            short sh, sl; splitf(f, sh, sl);
            h[j] = sh; lo[j] = sl;
        }
        w2h[n2] = h; w2l[n2] = lo;
    }

    float b1v[2][4];
#pragma unroll
    for (int nt = 0; nt < 2; ++nt)
#pragma unroll
        for (int r = 0; r < 4; ++r)
            b1v[nt][r] = b1[32 * w + 16 * nt + 4 * g + r];

    const int ncol = tid & 31;
    const float b2c = b2[ncol], gc = gamma[ncol], btc = beta[ncol];

    const int nbase = blockIdx.x * 32;
    const int n0 = min(nbase + c, N_NODES_C - 1);
    const int n1 = min(nbase + 16 + c, N_NODES_C - 1);
    const float rcp0 = 1.f / fmaxf(cnt[n0], 1.f);
    const float rcp1 = 1.f / fmaxf(cnt[n1], 1.f);

    f32x4 acc[2][2];
#pragma unroll
    for (int t = 0; t < 2; ++t)
#pragma unroll
        for (int nt = 0; nt < 2; ++nt) {
            f32x4 z = {0.f, 0.f, 0.f, 0.f};
            acc[t][nt] = z;
        }

    {
        bf16x8 bh0, bl0, bh1, bl1;
        ld8split(x + (size_t)n0 * 32 + 8 * g, 1.f, bh0, bl0);
        ld8split(x + (size_t)n1 * 32 + 8 * g, 1.f, bh1, bl1);
#pragma unroll
        for (int nt = 0; nt < 2; ++nt) {
            MFMA3(acc[0][nt], w1h[0][nt], w1l[0][nt], bh0, bl0);
            MFMA3(acc[1][nt], w1h[0][nt], w1l[0][nt], bh1, bl1);
        }
    }
    {
        const float* p0 = (g < 2) ? (agg + (size_t)n0 * 16 + 8 * g) : (u + 8 * (g - 2));
        const float* p1 = (g < 2) ? (agg + (size_t)n1 * 16 + 8 * g) : (u + 8 * (g - 2));
        const float sc0 = (g < 2) ? rcp0 : 1.f;
        const float sc1 = (g < 2) ? rcp1 : 1.f;
        bf16x8 bh0, bl0, bh1, bl1;
        ld8split(p0, sc0, bh0, bl0); ld8split(p1, sc1, bh1, bl1);
#pragma unroll
        for (int nt = 0; nt < 2; ++nt) {
            MFMA3(acc[0][nt], w1h[1][nt], w1l[1][nt], bh0, bl0);
            MFMA3(acc[1][nt], w1h[1][nt], w1l[1][nt], bh1, bl1);
        }
    }

#pragma unroll
    for (int t = 0; t < 2; ++t)
#pragma unroll
        for (int nt = 0; nt < 2; ++nt) {
            short4 hi4, lo4;
            float v0 = fmaxf(acc[t][nt][0] + b1v[nt][0], 0.f);
            float v1 = fmaxf(acc[t][nt][1] + b1v[nt][1], 0.f);
            float v2 = fmaxf(acc[t][nt][2] + b1v[nt][2], 0.f);
            float v3 = fmaxf(acc[t][nt][3] + b1v[nt][3], 0.f);
            splitf(v0, hi4.x, lo4.x); splitf(v1, hi4.y, lo4.y);
            splitf(v2, hi4.z, lo4.z); splitf(v3, hi4.w, lo4.w);
            const int grp = ((2 * nt + (g >> 1)) ^ csw) * 8 + 4 * (g & 1);
            *reinterpret_cast<short4*>(&hs[w][16 * t + c][0][grp]) = hi4;
            *reinterpret_cast<short4*>(&hs[w][16 * t + c][1][grp]) = lo4;
        }

    f32x4 acc2[2][2];
#pragma unroll
    for (int t = 0; t < 2; ++t)
#pragma unroll
        for (int n2 = 0; n2 < 2; ++n2) {
            f32x4 z = {0.f, 0.f, 0.f, 0.f};
            acc2[t][n2] = z;
        }
#pragma unroll
    for (int t = 0; t < 2; ++t) {
        const int rg = (g ^ csw) * 8;
        bf16x8 a2h = *reinterpret_cast<const bf16x8*>(&hs[w][16 * t + c][0][rg]);
        bf16x8 a2l = *reinterpret_cast<const bf16x8*>(&hs[w][16 * t + c][1][rg]);
#pragma unroll
        for (int n2 = 0; n2 < 2; ++n2) {
            acc2[t][n2] = __builtin_amdgcn_mfma_f32_16x16x32_bf16(a2h, w2h[n2], acc2[t][n2], 0, 0, 0);
            acc2[t][n2] = __builtin_amdgcn_mfma_f32_16x16x32_bf16(a2l, w2h[n2], acc2[t][n2], 0, 0, 0);
            acc2[t][n2] = __builtin_amdgcn_mfma_f32_16x16x32_bf16(a2h, w2l[n2], acc2[t][n2], 0, 0, 0);
        }
    }

#pragma unroll
    for (int t = 0; t < 2; ++t)
#pragma unroll
        for (int n2 = 0; n2 < 2; ++n2)
#pragma unroll
            for (int r = 0; r < 4; ++r)
                red[w][16 * t + 4 * g + r][16 * n2 + c] = acc2[t][n2][r];
    __syncthreads();

    float xsl = 0.f;
#pragma unroll
    for (int pass = 0; pass < 4; ++pass) {
        const int nrow = (tid >> 5) + 8 * pass;
        float o = red[0][nrow][ncol] + red[1][nrow][ncol] +
                  red[2][nrow][ncol] + red[3][nrow][ncol] + b2c;
        o = fmaxf(o, 0.f);
        float s = o, q = o * o;
        s += __shfl_xor(s, 1);   q += __shfl_xor(q, 1);
        s += __shfl_xor(s, 2);   q += __shfl_xor(q, 2);
        s += __shfl_xor(s, 4);   q += __shfl_xor(q, 4);
        s += __shfl_xor(s, 8);   q += __shfl_xor(q, 8);
        s += __shfl_xor(s, 16);  q += __shfl_xor(q, 16);
        const float mu = s * (1.f / 32.f);
        const float var = fmaxf(q * (1.f / 32.f) - mu * mu, 0.f);
        const float val = (o - mu) * rsqrtf(var + EPS_C) * gc + btc;
        const int node = nbase + nrow;
        if (node < N_NODES_C) {
            x_out[(size_t)node * 32 + ncol] = val;
            xsl += val;
        }
    }

    xsl += __shfl_xor(xsl, 32);
    if (l < 32) xsr[w][l] = xsl;
    __syncthreads();
    if (tid < 32) atomicAdd(&xsum[tid], xsr[0][tid] + xsr[1][tid] + xsr[2][tid] + xsr[3][tid]);
}

// ===========================================================================
// Global MLP (tiny, f32)
// ===========================================================================
__global__ __launch_bounds__(128) void global_kernel(
    const float* __restrict__ u,
    const float* __restrict__ W1, const float* __restrict__ b1,
    const float* __restrict__ W2, const float* __restrict__ b2,
    const float* __restrict__ esum, const float* __restrict__ xsum,
    float* __restrict__ u_out)
{
    __shared__ float gin[64];
    __shared__ float h[128];
    const int t = threadIdx.x;

    if (t < 16) gin[t] = u[t];
    else if (t < 48) gin[t] = xsum[t - 16] * (1.f / (float)N_NODES_C);
    else if (t < 64) gin[t] = esum[t - 48] * (1.f / (float)N_EDGES_C);
    __syncthreads();

    float hv = b1[t];
    for (int k = 0; k < 64; k++) hv = fmaf(gin[k], W1[(size_t)k * 128 + t], hv);
    h[t] = fmaxf(hv, 0.f);
    __syncthreads();

    if (t < 16) {
        float o = b2[t];
        for (int j = 0; j < 128; j++) o = fmaf(h[j], W2[(size_t)j * 16 + t], o);
        u_out[t] = fmaxf(o, 0.f);
    }
}

// ===========================================================================
extern "C" void kernel_launch(void* const* d_in, const int* in_sizes, int n_in,
                              void* d_out, int out_size, void* d_ws, size_t ws_size,
                              hipStream_t stream)
{
    const float* x    = (const float*)d_in[0];
    const float* ea   = (const float*)d_in[1];
    const float* u    = (const float*)d_in[2];
    const int*   src  = (const int*)d_in[3];
    const int*   dst  = (const int*)d_in[4];
    const float* eW1  = (const float*)d_in[5];
    const float* eb1  = (const float*)d_in[6];
    const float* eW2  = (const float*)d_in[7];
    const float* eb2  = (const float*)d_in[8];
    const float* eg   = (const float*)d_in[9];
    const float* ebt  = (const float*)d_in[10];
    const float* nW1  = (const float*)d_in[11];
    const float* nb1  = (const float*)d_in[12];
    const float* nW2  = (const float*)d_in[13];
    const float* nb2  = (const float*)d_in[14];
    const float* ng   = (const float*)d_in[15];
    const float* nbt  = (const float*)d_in[16];
    const float* gW1  = (const float*)d_in[17];
    const float* gb1  = (const float*)d_in[18];
    const float* gW2  = (const float*)d_in[19];
    const float* gb2  = (const float*)d_in[20];

    float* x_out = (float*)d_out;                              // 50000*32
    float* e_out = (float*)d_out + (size_t)N_NODES_C * 32;     // 1.6M*16
    float* u_out = e_out + (size_t)N_EDGES_C * 16;             // 16

    // ws layout (floats unless noted)
    float* agg8 = (float*)d_ws;                          // 8*800000 = 6.4M
    float* cnt8 = agg8 + (size_t)8 * 800000;             // 8*50000 = 400000
    float* esum = cnt8 + (size_t)8 * 50000;              // 16
    float* xsum = esum + 16;                             // 32
    float* agg  = xsum + 32;                             // 800000
    float* cntf = agg + 800000;                          // 50000
    unsigned short* xh = (unsigned short*)(cntf + 50000);  // 1.6M ushort
    unsigned short* xl = xh + (size_t)N_NODES_C * 32;       // 1.6M ushort

    // zero the atomic targets: agg8 + cnt8 + esum + xsum (contiguous)
    hipMemsetAsync(d_ws, 0,
                   ((size_t)8 * 800000 + 8 * 50000 + 48) * sizeof(float), stream);

    prep_x_kernel<<<(N_NODES_C * 32 / 4 + 255) / 256, 256, 0, stream>>>(x, xh, xl);

    edge_kernel<<<2000, 256, 0, stream>>>(
        xh, xl, ea, u, src, dst, eW1, eb1, eW2, eb2, eg, ebt,
        e_out, agg8, cnt8, esum);

    reduce_kernel<<<(N_NODES_C * 16 + 255) / 256, 256, 0, stream>>>(
        agg8, cnt8, agg, cntf);

    node_kernel<<<(N_NODES_C + 31) / 32, 256, 0, stream>>>(
        x, u, nW1, nb1, nW2, nb2, ng, nbt, agg, cntf, x_out, xsum);

    global_kernel<<<1, 128, 0, stream>>>(
        u, gW1, gb1, gW2, gb2, esum, xsum, u_out);
}

// Round 7
// 418.309 us; speedup vs baseline: 2.5438x; 1.0240x over previous
//
#include <hip/hip_runtime.h>

#define N_NODES_C 50000
#define N_EDGES_C 1600000
#define EPS_C 1e-5f

typedef __attribute__((ext_vector_type(8))) short bf16x8;
typedef __attribute__((ext_vector_type(4))) float f32x4;

static __device__ __forceinline__ unsigned short rne_bf(float f) {
    union { float f; unsigned int u; } v; v.f = f;
    unsigned int r = v.u + 0x7fffu + ((v.u >> 16) & 1u);  // RNE
    return (unsigned short)(r >> 16);
}
static __device__ __forceinline__ float bf2f(unsigned short h) {
    union { unsigned int u; float f; } v; v.u = ((unsigned int)h) << 16;
    return v.f;
}
static __device__ __forceinline__ void splitf(float x, short& hi, short& lo) {
    unsigned short h = rne_bf(x);
    hi = (short)h;
    lo = (short)rne_bf(x - bf2f(h));
}
static __device__ __forceinline__ void ld8split(const float* p, float scale,
                                                bf16x8& hi, bf16x8& lo) {
    float4 a = *reinterpret_cast<const float4*>(p);
    float4 b = *reinterpret_cast<const float4*>(p + 4);
    float v[8] = {a.x, a.y, a.z, a.w, b.x, b.y, b.z, b.w};
#pragma unroll
    for (int i = 0; i < 8; ++i) {
        short h, l;
        splitf(v[i] * scale, h, l);
        hi[i] = h; lo[i] = l;
    }
}

// 3-term split product: acc += (Ah+Al)@(Bh+Bl) minus lo@lo
#define MFMA3(acc, wh, wl, bh, bl)                                            \
    acc = __builtin_amdgcn_mfma_f32_16x16x32_bf16(wh, bh, acc, 0, 0, 0);      \
    acc = __builtin_amdgcn_mfma_f32_16x16x32_bf16(wl, bh, acc, 0, 0, 0);      \
    acc = __builtin_amdgcn_mfma_f32_16x16x32_bf16(wh, bl, acc, 0, 0, 0);

// ===========================================================================
// Pre-split x (50000x32 f32) into bf16 hi/lo planes.
// ===========================================================================
__global__ __launch_bounds__(256) void prep_x_kernel(
    const float* __restrict__ x,
    unsigned short* __restrict__ xh, unsigned short* __restrict__ xl)
{
    const int i = blockIdx.x * 256 + threadIdx.x;  // float4 index
    if (i >= (N_NODES_C * 32) / 4) return;
    float4 v = reinterpret_cast<const float4*>(x)[i];
    short4 h, l;
    splitf(v.x, h.x, l.x); splitf(v.y, h.y, l.y);
    splitf(v.z, h.z, l.z); splitf(v.w, h.w, l.w);
    reinterpret_cast<short4*>(xh)[i] = h;
    reinterpret_cast<short4*>(xl)[i] = l;
}

// ===========================================================================
// Fold the 8 XCD-local accumulator copies: agg = sum(agg8), cntf = sum(cnt8)
// ===========================================================================
__global__ __launch_bounds__(256) void reduce_kernel(
    const float* __restrict__ agg8, const float* __restrict__ cnt8,
    float* __restrict__ agg, float* __restrict__ cntf)
{
    const int i = blockIdx.x * 256 + threadIdx.x;
    if (i < N_NODES_C * 16) {
        float s = 0.f;
#pragma unroll
        for (int k = 0; k < 8; ++k) s += agg8[(size_t)k * (N_NODES_C * 16) + i];
        agg[i] = s;
    }
    if (i < N_NODES_C) {
        float s = 0.f;
#pragma unroll
        for (int k = 0; k < 8; ++k) s += cnt8[(size_t)k * N_NODES_C + i];
        cntf[i] = s;
    }
}

// ---- per-half-tile gather (issued early; consumed one stage later) --------
#define GATHER(E, S, D, EA0, EA1, SH, SL, DH, DL)                             \
    {                                                                         \
        if (glt2) {                                                           \
            const float* p_ = ea + (size_t)(E) * 16 + off8;                   \
            EA0 = *reinterpret_cast<const float4*>(p_);                       \
            EA1 = *reinterpret_cast<const float4*>(p_ + 4);                   \
        }                                                                     \
        SH = *reinterpret_cast<const bf16x8*>(xh + (size_t)(S) * 32 + 8 * g); \
        SL = *reinterpret_cast<const bf16x8*>(xl + (size_t)(S) * 32 + 8 * g); \
        DH = *reinterpret_cast<const bf16x8*>(xh + (size_t)(D) * 32 + 8 * g); \
        DL = *reinterpret_cast<const bf16x8*>(xl + (size_t)(D) * 32 + 8 * g); \
    }

// ---- one 16-edge half-tile: L1 (K=96) -> hs -> L2 -> ACC2 -----------------
#define COMPUTE_HALF(T, EA0, EA1, SH, SL, DH, DL, ACC2)                       \
    {                                                                         \
        f32x4 a0_, a1_;                                                       \
        a0_[0] = 0.f; a0_[1] = 0.f; a0_[2] = 0.f; a0_[3] = 0.f;               \
        a1_ = a0_;                                                            \
        bf16x8 b0h_, b0l_;                                                    \
        if (glt2) {                                                           \
            float vv_[8] = {EA0.x, EA0.y, EA0.z, EA0.w,                       \
                            EA1.x, EA1.y, EA1.z, EA1.w};                      \
            _Pragma("unroll")                                                 \
            for (int q_ = 0; q_ < 8; ++q_) {                                  \
                short hh_, ll_;                                               \
                splitf(vv_[q_], hh_, ll_);                                    \
                b0h_[q_] = hh_; b0l_[q_] = ll_;                               \
            }                                                                 \
        } else { b0h_ = uh; b0l_ = ul; }                                      \
        MFMA3(a0_, w1h[0][0], w1l[0][0], b0h_, b0l_);                         \
        MFMA3(a1_, w1h[0][1], w1l[0][1], b0h_, b0l_);                         \
        MFMA3(a0_, w1h[1][0], w1l[1][0], SH, SL);                             \
        MFMA3(a1_, w1h[1][1], w1l[1][1], SH, SL);                             \
        MFMA3(a0_, w1h[2][0], w1l[2][0], DH, DL);                             \
        MFMA3(a1_, w1h[2][1], w1l[2][1], DH, DL);                             \
        _Pragma("unroll")                                                     \
        for (int nt_ = 0; nt_ < 2; ++nt_) {                                   \
            f32x4 av_ = nt_ ? a1_ : a0_;                                      \
            short4 hi4_, lo4_;                                                \
            float v0_ = fmaxf(av_[0] + b1v[nt_][0], 0.f);                     \
            float v1_ = fmaxf(av_[1] + b1v[nt_][1], 0.f);                     \
            float v2_ = fmaxf(av_[2] + b1v[nt_][2], 0.f);                     \
            float v3_ = fmaxf(av_[3] + b1v[nt_][3], 0.f);                     \
            splitf(v0_, hi4_.x, lo4_.x); splitf(v1_, hi4_.y, lo4_.y);         \
            splitf(v2_, hi4_.z, lo4_.z); splitf(v3_, hi4_.w, lo4_.w);         \
            const int grp_ = ((2 * nt_ + (g >> 1)) ^ csw) * 8 + 4 * (g & 1);  \
            *reinterpret_cast<short4*>(&hs[w][16 * (T) + c][0][grp_]) = hi4_; \
            *reinterpret_cast<short4*>(&hs[w][16 * (T) + c][1][grp_]) = lo4_; \
        }                                                                     \
        {                                                                     \
            const int rg_ = (g ^ csw) * 8;                                    \
            bf16x8 a2h_ = *reinterpret_cast<const bf16x8*>(                   \
                &hs[w][16 * (T) + c][0][rg_]);                                \
            bf16x8 a2l_ = *reinterpret_cast<const bf16x8*>(                   \
                &hs[w][16 * (T) + c][1][rg_]);                                \
            ACC2[0] = 0.f; ACC2[1] = 0.f; ACC2[2] = 0.f; ACC2[3] = 0.f;       \
            ACC2 = __builtin_amdgcn_mfma_f32_16x16x32_bf16(a2h_, w2h, ACC2, 0, 0, 0); \
            ACC2 = __builtin_amdgcn_mfma_f32_16x16x32_bf16(a2l_, w2h, ACC2, 0, 0, 0); \
            ACC2 = __builtin_amdgcn_mfma_f32_16x16x32_bf16(a2h_, w2l, ACC2, 0, 0, 0); \
        }                                                                     \
    }

// ===========================================================================
// Edge MLP — R6 math/layout, software-pipelined gathers (2-stage register
// double-buffer at 16-edge half-tile granularity). XCD-local scatter atomics.
// ===========================================================================
__global__ __launch_bounds__(256) void edge_kernel(
    const unsigned short* __restrict__ xh, const unsigned short* __restrict__ xl,
    const float* __restrict__ ea, const float* __restrict__ u,
    const int* __restrict__ src, const int* __restrict__ dst,
    const float* __restrict__ W1, const float* __restrict__ b1,
    const float* __restrict__ W2, const float* __restrict__ b2,
    const float* __restrict__ gamma, const float* __restrict__ beta,
    float* __restrict__ e_out, float* __restrict__ agg8, float* __restrict__ cnt8,
    float* __restrict__ esum)
{
    __shared__ __attribute__((aligned(16))) unsigned short hs[4][32][2][40];
    __shared__ float red[2][4][32][17];
    __shared__ float esr[4][16];

    const int tid = threadIdx.x;
    const int w = tid >> 6, l = tid & 63, g = l >> 4, c = l & 15;
    const int csw = c >> 2;
    const int off8 = 8 * (g & 1);
    const bool glt2 = (g < 2);

    float* aggc = agg8 + (size_t)(blockIdx.x & 7) * (N_NODES_C * 16);
    float* cntc = cnt8 + (size_t)(blockIdx.x & 7) * N_NODES_C;

    // ---- W1 fragments, K-permuted (validated R6): kp -> orig row
    bf16x8 w1h[3][2], w1l[3][2];
#pragma unroll
    for (int kk = 0; kk < 3; ++kk)
#pragma unroll
        for (int nt = 0; nt < 2; ++nt) {
            bf16x8 h, lo;
#pragma unroll
            for (int j = 0; j < 8; ++j) {
                const int kp = 32 * kk + 8 * g + j;
                const int orig = (kp < 16) ? kp
                               : (kp < 32) ? (64 + kp)
                                           : (kp - 16);
                float f = W1[(size_t)orig * 128 + 32 * w + 16 * nt + c];
                short sh, sl; splitf(f, sh, sl);
                h[j] = sh; lo[j] = sl;
            }
            w1h[kk][nt] = h; w1l[kk][nt] = lo;
        }

    // ---- W2 slice fragments (K rows [32w,32w+32)), hi/lo
    bf16x8 w2h, w2l;
    {
        bf16x8 h, lo;
#pragma unroll
        for (int j = 0; j < 8; ++j) {
            float f = W2[(size_t)(32 * w + 8 * g + j) * 16 + c];
            short sh, sl; splitf(f, sh, sl);
            h[j] = sh; lo[j] = sl;
        }
        w2h = h; w2l = lo;
    }

    // ---- hoisted u fragments (lanes g>=2 in kk0)
    bf16x8 uh, ul;
    ld8split(u + off8, 1.f, uh, ul);

    float b1v[2][4];
#pragma unroll
    for (int nt = 0; nt < 2; ++nt)
#pragma unroll
        for (int r = 0; r < 4; ++r)
            b1v[nt][r] = b1[32 * w + 16 * nt + 4 * g + r];

    const int ecol = tid & 15;
    const float b2c = b2[ecol], gc = gamma[ecol], btc = beta[ecol];

    float esl = 0.f;
    const int base = blockIdx.x * 800;  // 2000 blocks * 25 iters * 32 edges

    // ---- pipeline prologue: indices for ht0/ht1, gather ht0
    int sA, dA, sB, dB;
    { const int e = base + c;       sA = src[e]; dA = dst[e]; }
    { const int e = base + 16 + c;  sB = src[e]; dB = dst[e]; }
    float4 eaA0, eaA1, eaB0, eaB1;
    bf16x8 shA, slA, dhA, dlA, shB, slB, dhB, dlB;
    GATHER(base + c, sA, dA, eaA0, eaA1, shA, slA, dhA, dlA);

#pragma unroll 1
    for (int i = 0; i < 25; ++i) {
        const int ebase = base + i * 32;

        // issue gather for ht=2i+1 (indices loaded one stage ago)
        GATHER(ebase + 16 + c, sB, dB, eaB0, eaB1, shB, slB, dhB, dlB);

        // epilogue dst prefetch (thread-major rows)
        const int erow_t = tid >> 4;
        const int dep0 = dst[ebase + erow_t];
        const int dep1 = dst[ebase + 16 + erow_t];

        // next even half-tile indices
        int sA2 = sA, dA2 = dA;
        if (i < 24) { const int e = ebase + 32 + c; sA2 = src[e]; dA2 = dst[e]; }

        // compute t = 0 (frags A)
        f32x4 acc2_0;
        COMPUTE_HALF(0, eaA0, eaA1, shA, slA, dhA, dlA, acc2_0);

        // refill A for ht=2i+2
        if (i < 24) GATHER(ebase + 32 + c, sA2, dA2, eaA0, eaA1, shA, slA, dhA, dlA);
        sA = sA2; dA = dA2;

        // next odd half-tile indices
        int sB2 = sB, dB2 = dB;
        if (i < 24) { const int e = ebase + 48 + c; sB2 = src[e]; dB2 = dst[e]; }

        // compute t = 1 (frags B)
        f32x4 acc2_1;
        COMPUTE_HALF(1, eaB0, eaB1, shB, slB, dhB, dlB, acc2_1);
        sB = sB2; dB = dB2;

        // ---- cross-wave partial reduce (dbuf; one barrier per iter)
        const int ib = i & 1;
#pragma unroll
        for (int r = 0; r < 4; ++r) red[ib][w][4 * g + r][c] = acc2_0[r];
#pragma unroll
        for (int r = 0; r < 4; ++r) red[ib][w][16 + 4 * g + r][c] = acc2_1[r];
        __syncthreads();

        // ---- epilogue: bias, ReLU, LN(16), store + XCD-local scatter
#pragma unroll
        for (int pass = 0; pass < 2; ++pass) {
            const int erow = erow_t + 16 * pass;
            float o = red[ib][0][erow][ecol] + red[ib][1][erow][ecol] +
                      red[ib][2][erow][ecol] + red[ib][3][erow][ecol] + b2c;
            o = fmaxf(o, 0.f);
            float s = o, q = o * o;
            s += __shfl_xor(s, 1);  q += __shfl_xor(q, 1);
            s += __shfl_xor(s, 2);  q += __shfl_xor(q, 2);
            s += __shfl_xor(s, 4);  q += __shfl_xor(q, 4);
            s += __shfl_xor(s, 8);  q += __shfl_xor(q, 8);
            const float mu = s * 0.0625f;
            const float var = fmaxf(q * 0.0625f - mu * mu, 0.f);
            const float val = (o - mu) * rsqrtf(var + EPS_C) * gc + btc;
            const int e2 = ebase + erow;
            e_out[(size_t)e2 * 16 + ecol] = val;
            const int d2 = pass ? dep1 : dep0;
            atomicAdd(&aggc[(size_t)d2 * 16 + ecol], val);
            if (ecol == 0) atomicAdd(&cntc[d2], 1.f);
            esl += val;
        }
    }

    // ---- fused e_out column-sum
    esl += __shfl_xor(esl, 16);
    esl += __shfl_xor(esl, 32);
    if (l < 16) esr[w][c] = esl;
    __syncthreads();
    if (tid < 16) atomicAdd(&esum[tid], esr[0][tid] + esr[1][tid] + esr[2][tid] + esr[3][tid]);
}

// ===========================================================================
// Node MLP (unchanged, validated). in[64]=[x(32), agg*rcp(16), u(16)]
// ===========================================================================
__global__ __launch_bounds__(256, 1) void node_kernel(
    const float* __restrict__ x, const float* __restrict__ u,
    const float* __restrict__ W1, const float* __restrict__ b1,
    const float* __restrict__ W2, const float* __restrict__ b2,
    const float* __restrict__ gamma, const float* __restrict__ beta,
    const float* __restrict__ agg, const float* __restrict__ cnt,
    float* __restrict__ x_out, float* __restrict__ xsum)
{
    __shared__ __attribute__((aligned(16))) unsigned short hs[4][32][2][40];
    __shared__ float red[4][32][36];
    __shared__ float xsr[4][32];

    const int tid = threadIdx.x;
    const int w = tid >> 6, l = tid & 63, g = l >> 4, c = l & 15;
    const int csw = c >> 2;

    bf16x8 w1h[2][2], w1l[2][2];
#pragma unroll
    for (int kk = 0; kk < 2; ++kk)
#pragma unroll
        for (int nt = 0; nt < 2; ++nt) {
            bf16x8 h, lo;
#pragma unroll
            for (int j = 0; j < 8; ++j) {
                float f = W1[(size_t)(32 * kk + 8 * g + j) * 128 + 32 * w + 16 * nt + c];
                short sh, sl; splitf(f, sh, sl);
                h[j] = sh; lo[j] = sl;
            }
            w1h[kk][nt] = h; w1l[kk][nt] = lo;
        }

    bf16x8 w2h[2], w2l[2];
#pragma unroll
    for (int n2 = 0; n2 < 2; ++n2) {
        bf16x8 h, lo;
#pragma unroll
        for (int j = 0; j < 8; ++j) {
            float f = W2[(size_t)(32 * w + 8 * g + j) * 32 + 16 * n2 + c];
            short sh, sl; splitf(f, sh, sl);
            h[j] = sh; lo[j] = sl;
        }
        w2h[n2] = h; w2l[n2] = lo;
    }

    float b1v[2][4];
#pragma unroll
    for (int nt = 0; nt < 2; ++nt)
#pragma unroll
        for (int r = 0; r < 4; ++r)
            b1v[nt][r] = b1[32 * w + 16 * nt + 4 * g + r];

    const int ncol = tid & 31;
    const float b2c = b2[ncol], gc = gamma[ncol], btc = beta[ncol];

    const int nbase = blockIdx.x * 32;
    const int n0 = min(nbase + c, N_NODES_C - 1);
    const int n1 = min(nbase + 16 + c, N_NODES_C - 1);
    const float rcp0 = 1.f / fmaxf(cnt[n0], 1.f);
    const float rcp1 = 1.f / fmaxf(cnt[n1], 1.f);

    f32x4 acc[2][2];
#pragma unroll
    for (int t = 0; t < 2; ++t)
#pragma unroll
        for (int nt = 0; nt < 2; ++nt) {
            f32x4 z = {0.f, 0.f, 0.f, 0.f};
            acc[t][nt] = z;
        }

    {
        bf16x8 bh0, bl0, bh1, bl1;
        ld8split(x + (size_t)n0 * 32 + 8 * g, 1.f, bh0, bl0);
        ld8split(x + (size_t)n1 * 32 + 8 * g, 1.f, bh1, bl1);
#pragma unroll
        for (int nt = 0; nt < 2; ++nt) {
            MFMA3(acc[0][nt], w1h[0][nt], w1l[0][nt], bh0, bl0);
            MFMA3(acc[1][nt], w1h[0][nt], w1l[0][nt], bh1, bl1);
        }
    }
    {
        const float* p0 = (g < 2) ? (agg + (size_t)n0 * 16 + 8 * g) : (u + 8 * (g - 2));
        const float* p1 = (g < 2) ? (agg + (size_t)n1 * 16 + 8 * g) : (u + 8 * (g - 2));
        const float sc0 = (g < 2) ? rcp0 : 1.f;
        const float sc1 = (g < 2) ? rcp1 : 1.f;
        bf16x8 bh0, bl0, bh1, bl1;
        ld8split(p0, sc0, bh0, bl0); ld8split(p1, sc1, bh1, bl1);
#pragma unroll
        for (int nt = 0; nt < 2; ++nt) {
            MFMA3(acc[0][nt], w1h[1][nt], w1l[1][nt], bh0, bl0);
            MFMA3(acc[1][nt], w1h[1][nt], w1l[1][nt], bh1, bl1);
        }
    }

#pragma unroll
    for (int t = 0; t < 2; ++t)
#pragma unroll
        for (int nt = 0; nt < 2; ++nt) {
            short4 hi4, lo4;
            float v0 = fmaxf(acc[t][nt][0] + b1v[nt][0], 0.f);
            float v1 = fmaxf(acc[t][nt][1] + b1v[nt][1], 0.f);
            float v2 = fmaxf(acc[t][nt][2] + b1v[nt][2], 0.f);
            float v3 = fmaxf(acc[t][nt][3] + b1v[nt][3], 0.f);
            splitf(v0, hi4.x, lo4.x); splitf(v1, hi4.y, lo4.y);
            splitf(v2, hi4.z, lo4.z); splitf(v3, hi4.w, lo4.w);
            const int grp = ((2 * nt + (g >> 1)) ^ csw) * 8 + 4 * (g & 1);
            *reinterpret_cast<short4*>(&hs[w][16 * t + c][0][grp]) = hi4;
            *reinterpret_cast<short4*>(&hs[w][16 * t + c][1][grp]) = lo4;
        }

    f32x4 acc2[2][2];
#pragma unroll
    for (int t = 0; t < 2; ++t)
#pragma unroll
        for (int n2 = 0; n2 < 2; ++n2) {
            f32x4 z = {0.f, 0.f, 0.f, 0.f};
            acc2[t][n2] = z;
        }
#pragma unroll
    for (int t = 0; t < 2; ++t) {
        const int rg = (g ^ csw) * 8;
        bf16x8 a2h = *reinterpret_cast<const bf16x8*>(&hs[w][16 * t + c][0][rg]);
        bf16x8 a2l = *reinterpret_cast<const bf16x8*>(&hs[w][16 * t + c][1][rg]);
#pragma unroll
        for (int n2 = 0; n2 < 2; ++n2) {
            acc2[t][n2] = __builtin_amdgcn_mfma_f32_16x16x32_bf16(a2h, w2h[n2], acc2[t][n2], 0, 0, 0);
            acc2[t][n2] = __builtin_amdgcn_mfma_f32_16x16x32_bf16(a2l, w2h[n2], acc2[t][n2], 0, 0, 0);
            acc2[t][n2] = __builtin_amdgcn_mfma_f32_16x16x32_bf16(a2h, w2l[n2], acc2[t][n2], 0, 0, 0);
        }
    }

#pragma unroll
    for (int t = 0; t < 2; ++t)
#pragma unroll
        for (int n2 = 0; n2 < 2; ++n2)
#pragma unroll
            for (int r = 0; r < 4; ++r)
                red[w][16 * t + 4 * g + r][16 * n2 + c] = acc2[t][n2][r];
    __syncthreads();

    float xsl = 0.f;
#pragma unroll
    for (int pass = 0; pass < 4; ++pass) {
        const int nrow = (tid >> 5) + 8 * pass;
        float o = red[0][nrow][ncol] + red[1][nrow][ncol] +
                  red[2][nrow][ncol] + red[3][nrow][ncol] + b2c;
        o = fmaxf(o, 0.f);
        float s = o, q = o * o;
        s += __shfl_xor(s, 1);   q += __shfl_xor(q, 1);
        s += __shfl_xor(s, 2);   q += __shfl_xor(q, 2);
        s += __shfl_xor(s, 4);   q += __shfl_xor(q, 4);
        s += __shfl_xor(s, 8);   q += __shfl_xor(q, 8);
        s += __shfl_xor(s, 16);  q += __shfl_xor(q, 16);
        const float mu = s * (1.f / 32.f);
        const float var = fmaxf(q * (1.f / 32.f) - mu * mu, 0.f);
        const float val = (o - mu) * rsqrtf(var + EPS_C) * gc + btc;
        const int node = nbase + nrow;
        if (node < N_NODES_C) {
            x_out[(size_t)node * 32 + ncol] = val;
            xsl += val;
        }
    }

    xsl += __shfl_xor(xsl, 32);
    if (l < 32) xsr[w][l] = xsl;
    __syncthreads();
    if (tid < 32) atomicAdd(&xsum[tid], xsr[0][tid] + xsr[1][tid] + xsr[2][tid] + xsr[3][tid]);
}

// ===========================================================================
// Global MLP (tiny, f32)
// ===========================================================================
__global__ __launch_bounds__(128) void global_kernel(
    const float* __restrict__ u,
    const float* __restrict__ W1, const float* __restrict__ b1,
    const float* __restrict__ W2, const float* __restrict__ b2,
    const float* __restrict__ esum, const float* __restrict__ xsum,
    float* __restrict__ u_out)
{
    __shared__ float gin[64];
    __shared__ float h[128];
    const int t = threadIdx.x;

    if (t < 16) gin[t] = u[t];
    else if (t < 48) gin[t] = xsum[t - 16] * (1.f / (float)N_NODES_C);
    else if (t < 64) gin[t] = esum[t - 48] * (1.f / (float)N_EDGES_C);
    __syncthreads();

    float hv = b1[t];
    for (int k = 0; k < 64; k++) hv = fmaf(gin[k], W1[(size_t)k * 128 + t], hv);
    h[t] = fmaxf(hv, 0.f);
    __syncthreads();

    if (t < 16) {
        float o = b2[t];
        for (int j = 0; j < 128; j++) o = fmaf(h[j], W2[(size_t)j * 16 + t], o);
        u_out[t] = fmaxf(o, 0.f);
    }
}

// ===========================================================================
extern "C" void kernel_launch(void* const* d_in, const int* in_sizes, int n_in,
                              void* d_out, int out_size, void* d_ws, size_t ws_size,
                              hipStream_t stream)
{
    const float* x    = (const float*)d_in[0];
    const float* ea   = (const float*)d_in[1];
    const float* u    = (const float*)d_in[2];
    const int*   src  = (const int*)d_in[3];
    const int*   dst  = (const int*)d_in[4];
    const float* eW1  = (const float*)d_in[5];
    const float* eb1  = (const float*)d_in[6];
    const float* eW2  = (const float*)d_in[7];
    const float* eb2  = (const float*)d_in[8];
    const float* eg   = (const float*)d_in[9];
    const float* ebt  = (const float*)d_in[10];
    const float* nW1  = (const float*)d_in[11];
    const float* nb1  = (const float*)d_in[12];
    const float* nW2  = (const float*)d_in[13];
    const float* nb2  = (const float*)d_in[14];
    const float* ng   = (const float*)d_in[15];
    const float* nbt  = (const float*)d_in[16];
    const float* gW1  = (const float*)d_in[17];
    const float* gb1  = (const float*)d_in[18];
    const float* gW2  = (const float*)d_in[19];
    const float* gb2  = (const float*)d_in[20];

    float* x_out = (float*)d_out;                              // 50000*32
    float* e_out = (float*)d_out + (size_t)N_NODES_C * 32;     // 1.6M*16
    float* u_out = e_out + (size_t)N_EDGES_C * 16;             // 16

    // ws layout (floats unless noted)
    float* agg8 = (float*)d_ws;                          // 8*800000 = 6.4M
    float* cnt8 = agg8 + (size_t)8 * 800000;             // 8*50000 = 400000
    float* esum = cnt8 + (size_t)8 * 50000;              // 16
    float* xsum = esum + 16;                             // 32
    float* agg  = xsum + 32;                             // 800000
    float* cntf = agg + 800000;                          // 50000
    unsigned short* xh = (unsigned short*)(cntf + 50000);  // 1.6M ushort
    unsigned short* xl = xh + (size_t)N_NODES_C * 32;       // 1.6M ushort

    // zero the atomic targets: agg8 + cnt8 + esum + xsum (contiguous)
    hipMemsetAsync(d_ws, 0,
                   ((size_t)8 * 800000 + 8 * 50000 + 48) * sizeof(float), stream);

    prep_x_kernel<<<(N_NODES_C * 32 / 4 + 255) / 256, 256, 0, stream>>>(x, xh, xl);

    edge_kernel<<<2000, 256, 0, stream>>>(
        xh, xl, ea, u, src, dst, eW1, eb1, eW2, eb2, eg, ebt,
        e_out, agg8, cnt8, esum);

    reduce_kernel<<<(N_NODES_C * 16 + 255) / 256, 256, 0, stream>>>(
        agg8, cnt8, agg, cntf);

    node_kernel<<<(N_NODES_C + 31) / 32, 256, 0, stream>>>(
        x, u, nW1, nb1, nW2, nb2, ng, nbt, agg, cntf, x_out, xsum);

    global_kernel<<<1, 128, 0, stream>>>(
        u, gW1, gb1, gW2, gb2, esum, xsum, u_out);
}